// Round 2
// baseline (2976.505 us; speedup 1.0000x reference)
//
#include <hip/hip_runtime.h>
#include <hip/hip_bf16.h>
#include <math.h>

#define BQ   1024
#define CAP  100000
#define KDIM 2048
#define CDIM 384
#define TOPK 5
#define MT   8            // 1024/128 row tiles
#define NT   782          // ceil(100000/128) col tiles
#define NCAND (NT*TOPK)   // 3910 candidates per row
#define KPAD 56           // LDS row stride (bf16 elems): 112B = 7*16B, 16B-aligned rows
#define SIMPAD 129        // sim tile LDS stride (f32)

typedef __bf16 bf16x8 __attribute__((ext_vector_type(8)));
typedef float  f32x4  __attribute__((ext_vector_type(4)));

__device__ __forceinline__ unsigned short f2bf(float f) {
  unsigned int u = __float_as_uint(f);
  u += 0x7FFF + ((u >> 16) & 1);   // RNE
  return (unsigned short)(u >> 16);
}

// ---------------- K1: bf16 MFMA GEMM tile + per-(row,coltile) top-5 candidates ----------------
__global__ __launch_bounds__(256) void k_gemm_cand(
    const float* __restrict__ Aq, const float* __restrict__ Bb,
    const int* __restrict__ valid,      // int32 mask (harness converts bool -> int32)
    float* __restrict__ cand_s, int* __restrict__ cand_c)
{
  __shared__ __align__(16) unsigned char smem[128*SIMPAD*4];  // 66048 B, aliased
  __shared__ int s_valid[128];
  unsigned short* lds_a = (unsigned short*)smem;              // [128][KPAD]
  unsigned short* lds_b = lds_a + 128*KPAD;                   // [128][KPAD]
  float* sim = (float*)smem;                                  // [128][SIMPAD]

  const int tid = threadIdx.x;
  const int bid = blockIdx.x;
  const int rt = bid & 7;       // row tile (fast) -> coltile-major order for L2/L3 bank reuse
  const int ct = bid >> 3;      // col tile
  const int lane = tid & 63;
  const int wid  = tid >> 6;
  const int wr = wid >> 1;      // wave row 0/1 (64 rows each)
  const int wc = wid & 1;       // wave col 0/1
  const int lrow = lane & 15;
  const int lko  = (lane >> 4) * 8;     // k offset (elems) within fragment

  const int arow0 = rt * 128;
  const int brow0 = ct * 128;

  if (tid < 128) {
    int col = brow0 + tid;
    s_valid[tid] = (col < CAP) ? valid[col] : 0;
  }

  f32x4 acc[4][4];
  const f32x4 zero4 = {0.f, 0.f, 0.f, 0.f};
  #pragma unroll
  for (int m = 0; m < 4; ++m)
    #pragma unroll
    for (int n = 0; n < 4; ++n) acc[m][n] = zero4;

  for (int k0 = 0; k0 < KDIM; k0 += 32) {
    // stage 128x32 fp32 of A and B -> bf16 LDS (4 float4 per thread per matrix)
    #pragma unroll
    for (int it = 0; it < 4; ++it) {
      int idx = it * 256 + tid;
      int row = idx >> 3;
      int kq  = (idx & 7) * 4;
      float4 av = *reinterpret_cast<const float4*>(&Aq[(size_t)(arow0 + row) * KDIM + k0 + kq]);
      ushort4 pa = make_ushort4(f2bf(av.x), f2bf(av.y), f2bf(av.z), f2bf(av.w));
      *reinterpret_cast<ushort4*>(&lds_a[row * KPAD + kq]) = pa;
      int br = brow0 + row;
      float4 bv = make_float4(0.f, 0.f, 0.f, 0.f);
      if (br < CAP) bv = *reinterpret_cast<const float4*>(&Bb[(size_t)br * KDIM + k0 + kq]);
      ushort4 pb = make_ushort4(f2bf(bv.x), f2bf(bv.y), f2bf(bv.z), f2bf(bv.w));
      *reinterpret_cast<ushort4*>(&lds_b[row * KPAD + kq]) = pb;
    }
    __syncthreads();

    bf16x8 af[4], bfr[4];
    #pragma unroll
    for (int m = 0; m < 4; ++m)
      af[m] = *reinterpret_cast<const bf16x8*>(&lds_a[(wr*64 + m*16 + lrow) * KPAD + lko]);
    #pragma unroll
    for (int n = 0; n < 4; ++n)
      bfr[n] = *reinterpret_cast<const bf16x8*>(&lds_b[(wc*64 + n*16 + lrow) * KPAD + lko]);

    #pragma unroll
    for (int m = 0; m < 4; ++m)
      #pragma unroll
      for (int n = 0; n < 4; ++n)
        acc[m][n] = __builtin_amdgcn_mfma_f32_16x16x32_bf16(af[m], bfr[n], acc[m][n], 0, 0, 0);
    __syncthreads();
  }

  // write 128x128 raw-dot tile to LDS (C/D layout: col=lane&15, row=(lane>>4)*4+reg)
  #pragma unroll
  for (int m = 0; m < 4; ++m) {
    #pragma unroll
    for (int n = 0; n < 4; ++n) {
      int col  = wc*64 + n*16 + (lane & 15);
      int rowb = wr*64 + m*16 + (lane >> 4) * 4;
      #pragma unroll
      for (int r = 0; r < 4; ++r)
        sim[(rowb + r) * SIMPAD + col] = acc[m][n][r];
    }
  }
  __syncthreads();

  // per-row top-5 within this col tile (strict > keeps lowest col on ties)
  if (tid < 128) {
    float s[TOPK]; int c[TOPK];
    #pragma unroll
    for (int i = 0; i < TOPK; ++i) { s[i] = -INFINITY; c[i] = 0x7FFFFFFF; }
    for (int j = 0; j < 128; ++j) {
      int col = brow0 + j;
      if (col >= CAP) break;
      if (!s_valid[j]) continue;
      float v = sim[tid * SIMPAD + j];
      if (v > s[TOPK-1]) {
        int p = TOPK - 1;
        while (p > 0 && v > s[p-1]) { s[p] = s[p-1]; c[p] = c[p-1]; --p; }
        s[p] = v; c[p] = col;
      }
    }
    size_t base = ((size_t)(arow0 + tid) * NT + ct) * TOPK;
    #pragma unroll
    for (int i = 0; i < TOPK; ++i) { cand_s[base + i] = s[i]; cand_c[base + i] = c[i]; }
  }
}

// ---------------- K2: merge candidates -> top-32 -> exact fp64 rescore -> output ----------------
__global__ __launch_bounds__(256) void k_select(
    const float* __restrict__ Aq, const float* __restrict__ Bb,
    const float* __restrict__ content,
    const float* __restrict__ cand_s, const int* __restrict__ cand_c,
    float* __restrict__ out)
{
  __shared__ float  s_s[NCAND];
  __shared__ int    s_c[NCAND];
  __shared__ float  s_q[KDIM];
  __shared__ float  r_s[256];
  __shared__ int    r_c[256];
  __shared__ int    r_p[256];
  __shared__ int    sel_c[32];
  __shared__ double sel_v[32];
  __shared__ int    o_col[TOPK];
  __shared__ int    o_ok[TOPK];

  const int tid = threadIdx.x;
  const int b   = blockIdx.x;

  size_t cbase = (size_t)b * NCAND;
  for (int i = tid; i < NCAND; i += 256) { s_s[i] = cand_s[cbase + i]; s_c[i] = cand_c[cbase + i]; }
  for (int i = tid; i < KDIM; i += 256) s_q[i] = Aq[(size_t)b * KDIM + i];
  if (tid < TOPK) { o_ok[tid] = 0; o_col[tid] = 0; }
  __syncthreads();

  // iterative argmax x32 (tie -> lowest col)
  for (int k = 0; k < 32; ++k) {
    float best = -INFINITY; int bc = 0x7FFFFFFF; int bp = 0;
    for (int i = tid; i < NCAND; i += 256) {
      float v = s_s[i]; int cc = s_c[i];
      if (v > best || (v == best && cc < bc)) { best = v; bc = cc; bp = i; }
    }
    r_s[tid] = best; r_c[tid] = bc; r_p[tid] = bp;
    __syncthreads();
    for (int off = 128; off > 0; off >>= 1) {
      if (tid < off) {
        float v = r_s[tid + off]; int cc = r_c[tid + off];
        if (v > r_s[tid] || (v == r_s[tid] && cc < r_c[tid])) {
          r_s[tid] = v; r_c[tid] = cc; r_p[tid] = r_p[tid + off];
        }
      }
      __syncthreads();
    }
    if (tid == 0) { sel_c[k] = r_c[0]; s_s[r_p[0]] = -INFINITY; }
    __syncthreads();
  }

  // exact fp64 rescore: 4 waves x 8 candidates, wave-parallel dot over K=2048
  const int wid = tid >> 6, lane = tid & 63;
  for (int q = 0; q < 8; ++q) {
    int i  = wid * 8 + q;
    int cc = sel_c[i];
    bool ok = (cc >= 0 && cc < CAP);
    double a = 0.0;
    if (ok) {
      const float* brow = &Bb[(size_t)cc * KDIM];
      #pragma unroll 4
      for (int j = 0; j < KDIM / 64; ++j) {
        int kk = j * 64 + lane;
        a += (double)s_q[kk] * (double)brow[kk];
      }
    }
    #pragma unroll
    for (int off = 32; off > 0; off >>= 1) a += __shfl_down(a, off);
    if (lane == 0) sel_v[i] = ok ? a : -INFINITY;
  }
  __syncthreads();

  // exact ranking of the 32 (score desc, col asc, position asc), emit top-5
  if (tid < 32) {
    double my = sel_v[tid]; int mc = sel_c[tid];
    int rank = 0;
    for (int j = 0; j < 32; ++j) {
      double ov = sel_v[j]; int oc = sel_c[j];
      if (ov > my || (ov == my && (oc < mc || (oc == mc && j < tid)))) ++rank;
    }
    if (rank < TOPK) {
      double simv = my * (1.0 / 40.0);
      int pass = (my != -INFINITY) && (simv >= 0.3);
      out[(size_t)BQ * TOPK * CDIM + (size_t)b * TOPK + rank] = pass ? (float)simv : 0.0f;
      o_col[rank] = mc; o_ok[rank] = pass;
    }
  }
  __syncthreads();

  // gather contents [TOPK][CDIM]
  for (int idx = tid; idx < TOPK * CDIM; idx += 256) {
    int slot = idx / CDIM;
    int d    = idx - slot * CDIM;
    float v  = 0.f;
    if (o_ok[slot]) v = content[(size_t)o_col[slot] * CDIM + d];
    out[(size_t)b * TOPK * CDIM + idx] = v;
  }
}

extern "C" void kernel_launch(void* const* d_in, const int* in_sizes, int n_in,
                              void* d_out, int out_size, void* d_ws, size_t ws_size,
                              hipStream_t stream) {
  const float* q        = (const float*)d_in[0];
  const float* bank     = (const float*)d_in[1];
  const float* content  = (const float*)d_in[2];
  const int*   valid    = (const int*)d_in[3];
  float* out = (float*)d_out;

  float* cand_s = (float*)d_ws;                                  // [BQ][NT][5] f32
  int*   cand_c = (int*)((char*)d_ws + (size_t)BQ * NCAND * 4);  // [BQ][NT][5] i32
  // total ws use: 1024*3910*8 = 32,030,720 B

  k_gemm_cand<<<dim3(MT * NT), dim3(256), 0, stream>>>(q, bank, valid, cand_s, cand_c);
  k_select<<<dim3(BQ), dim3(256), 0, stream>>>(q, bank, content, cand_s, cand_c, out);
}

// Round 3
// 1448.233 us; speedup vs baseline: 2.0553x; 2.0553x over previous
//
#include <hip/hip_runtime.h>
#include <hip/hip_bf16.h>
#include <math.h>

#define BQ   1024
#define CAP  100000
#define KDIM 2048
#define CDIM 384
#define TOPK 5
#define MT   8            // 1024/128 row tiles
#define NT   782          // ceil(100000/128) col tiles
#define NCAND (NT*TOPK)   // 3910 candidates per row
#define KPAD 56           // (fallback path) LDS row stride bf16
#define SIMPAD 129        // (fallback path) sim LDS stride f32

// bf16-path workspace layout (bytes)
#define WS_BBF   0UL
#define WS_ABF   409600000UL
#define WS_CS    413794304UL
#define WS_CC    429809664UL
#define WS_NEED  445825024UL

typedef __bf16 bf16x8 __attribute__((ext_vector_type(8)));
typedef float  f32x4  __attribute__((ext_vector_type(4)));
typedef unsigned short ushort8 __attribute__((ext_vector_type(8)));

__device__ __forceinline__ unsigned short f2bf(float f) {
  unsigned int u = __float_as_uint(f);
  u += 0x7FFF + ((u >> 16) & 1);   // RNE
  return (unsigned short)(u >> 16);
}

// ---------------- K0: fp32 -> bf16 conversion (grid-stride, 32B read / 16B write per thread-iter) ----
__global__ __launch_bounds__(256) void k_cvt(const float* __restrict__ src,
                                             unsigned short* __restrict__ dst, int n8) {
  int stride = gridDim.x * 256;
  for (int i = blockIdx.x * 256 + threadIdx.x; i < n8; i += stride) {
    const float4* s = reinterpret_cast<const float4*>(src) + (size_t)i * 2;
    float4 a = s[0], b = s[1];
    ushort8 o;
    o[0]=f2bf(a.x); o[1]=f2bf(a.y); o[2]=f2bf(a.z); o[3]=f2bf(a.w);
    o[4]=f2bf(b.x); o[5]=f2bf(b.y); o[6]=f2bf(b.z); o[7]=f2bf(b.w);
    *(reinterpret_cast<ushort8*>(dst) + i) = o;
  }
}

// ---------------- K1 (bf16 path): m97-style GEMM + per-(row,coltile) top-5 ----------------
__global__ __launch_bounds__(256) void k_gemm_bf16(
    const unsigned short* __restrict__ Abf, const unsigned short* __restrict__ Bbf,
    const int* __restrict__ valid,
    float* __restrict__ cand_s, int* __restrict__ cand_c)
{
  // union: staging (A 8KB + B 8KB) | sim chunk [128][33] f32 (16896B)
  __shared__ __align__(16) unsigned char smem[16896];
  __shared__ int s_valid[128];
  unsigned short* lds_a = (unsigned short*)smem;   // [128][32]
  unsigned short* lds_b = lds_a + 128*32;          // [128][32]
  float* simc = (float*)smem;                      // [128][33]

  const int bid = blockIdx.x;
  const int g = bid >> 6, sub = bid & 63;
  const int rt = sub >> 3;
  const int ct = g * 8 + (sub & 7);      // bid%8 == ct%8  -> same B-tile blocks share an XCD
  if (ct >= NT) return;

  const int tid = threadIdx.x;
  const int lane = tid & 63;
  const int w    = tid >> 6;
  const int wr = w >> 1, wc = w & 1;
  const int lrow = lane & 15;
  const int lko  = (lane >> 4) * 8;

  const int arow0 = rt * 128;
  const int brow0 = ct * 128;

  if (tid < 128) s_valid[tid] = (brow0 + tid < CAP) ? valid[brow0 + tid] : 0;

  // per-lane staging coordinates (linear LDS <-> pre-swizzled global source)
  const int srow = (lane >> 2);          // + w*32 + i*16
  const int skel = (lane & 3) * 8;

  f32x4 acc[4][4];
  const f32x4 zero4 = {0.f,0.f,0.f,0.f};
  #pragma unroll
  for (int m = 0; m < 4; ++m)
    #pragma unroll
    for (int n = 0; n < 4; ++n) acc[m][n] = zero4;

  for (int k0 = 0; k0 < KDIM; k0 += 32) {
    #pragma unroll
    for (int i = 0; i < 2; ++i) {
      int row = w * 32 + i * 16 + srow;
      const unsigned short* gA = Abf + (size_t)(arow0 + row) * KDIM + k0 + skel;
      unsigned short* lA = lds_a + w * 1024 + i * 512;          // wave-uniform base
      __builtin_amdgcn_global_load_lds(
          (const __attribute__((address_space(1))) unsigned int*)gA,
          (__attribute__((address_space(3))) unsigned int*)lA, 16, 0, 0);
      int rowb = brow0 + row; if (rowb >= CAP) rowb = CAP - 1;  // clamped; masked via s_valid
      const unsigned short* gB = Bbf + (size_t)rowb * KDIM + k0 + skel;
      unsigned short* lB = lds_b + w * 1024 + i * 512;
      __builtin_amdgcn_global_load_lds(
          (const __attribute__((address_space(1))) unsigned int*)gB,
          (__attribute__((address_space(3))) unsigned int*)lB, 16, 0, 0);
    }
    __syncthreads();   // compiler drains vmcnt before barrier

    bf16x8 af[4], bfr[4];
    #pragma unroll
    for (int m = 0; m < 4; ++m)
      af[m] = *reinterpret_cast<const bf16x8*>(&lds_a[(wr*64 + m*16 + lrow) * 32 + lko]);
    #pragma unroll
    for (int n = 0; n < 4; ++n)
      bfr[n] = *reinterpret_cast<const bf16x8*>(&lds_b[(wc*64 + n*16 + lrow) * 32 + lko]);

    #pragma unroll
    for (int m = 0; m < 4; ++m)
      #pragma unroll
      for (int n = 0; n < 4; ++n)
        acc[m][n] = __builtin_amdgcn_mfma_f32_16x16x32_bf16(af[m], bfr[n], acc[m][n], 0, 0, 0);
    __syncthreads();
  }

  // epilogue: 4 chunks of 32 cols through a 17KB sim slab; running top-5 in regs
  float ts[TOPK]; int tc[TOPK];
  #pragma unroll
  for (int i = 0; i < TOPK; ++i) { ts[i] = -INFINITY; tc[i] = 0x7FFFFFFF; }

  for (int c = 0; c < 4; ++c) {
    __syncthreads();
    if (wc == (c >> 1)) {
      #pragma unroll
      for (int m = 0; m < 4; ++m) {
        #pragma unroll
        for (int nn = 0; nn < 2; ++nn) {
          int n = (c & 1) * 2 + nn;
          int rowb = wr*64 + m*16 + (lane >> 4) * 4;
          int lcol = nn*16 + lrow;
          #pragma unroll
          for (int r = 0; r < 4; ++r)
            simc[(rowb + r) * 33 + lcol] = acc[m][n][r];
        }
      }
    }
    __syncthreads();
    if (tid < 128) {
      #pragma unroll 4
      for (int j = 0; j < 32; ++j) {
        int jj = c * 32 + j;
        float v = simc[tid * 33 + j];
        if (s_valid[jj] && v > ts[TOPK-1]) {
          int col = brow0 + jj;
          int p = TOPK - 1;
          while (p > 0 && v > ts[p-1]) { ts[p] = ts[p-1]; tc[p] = tc[p-1]; --p; }
          ts[p] = v; tc[p] = col;
        }
      }
    }
  }

  if (tid < 128) {
    size_t base = ((size_t)(arow0 + tid) * NT + ct) * TOPK;
    #pragma unroll
    for (int i = 0; i < TOPK; ++i) { cand_s[base + i] = ts[i]; cand_c[base + i] = tc[i]; }
  }
}

// ---------------- K1 fallback (fp32 staging) — the round-2 passing kernel ----------------
__global__ __launch_bounds__(256) void k_gemm_cand(
    const float* __restrict__ Aq, const float* __restrict__ Bb,
    const int* __restrict__ valid,
    float* __restrict__ cand_s, int* __restrict__ cand_c)
{
  __shared__ __align__(16) unsigned char smem[128*SIMPAD*4];
  __shared__ int s_valid[128];
  unsigned short* lds_a = (unsigned short*)smem;
  unsigned short* lds_b = lds_a + 128*KPAD;
  float* sim = (float*)smem;

  const int tid = threadIdx.x;
  const int bid = blockIdx.x;
  const int rt = bid & 7;
  const int ct = bid >> 3;
  const int lane = tid & 63;
  const int wid  = tid >> 6;
  const int wr = wid >> 1;
  const int wc = wid & 1;
  const int lrow = lane & 15;
  const int lko  = (lane >> 4) * 8;

  const int arow0 = rt * 128;
  const int brow0 = ct * 128;

  if (tid < 128) {
    int col = brow0 + tid;
    s_valid[tid] = (col < CAP) ? valid[col] : 0;
  }

  f32x4 acc[4][4];
  const f32x4 zero4 = {0.f, 0.f, 0.f, 0.f};
  #pragma unroll
  for (int m = 0; m < 4; ++m)
    #pragma unroll
    for (int n = 0; n < 4; ++n) acc[m][n] = zero4;

  for (int k0 = 0; k0 < KDIM; k0 += 32) {
    #pragma unroll
    for (int it = 0; it < 4; ++it) {
      int idx = it * 256 + tid;
      int row = idx >> 3;
      int kq  = (idx & 7) * 4;
      float4 av = *reinterpret_cast<const float4*>(&Aq[(size_t)(arow0 + row) * KDIM + k0 + kq]);
      ushort4 pa = make_ushort4(f2bf(av.x), f2bf(av.y), f2bf(av.z), f2bf(av.w));
      *reinterpret_cast<ushort4*>(&lds_a[row * KPAD + kq]) = pa;
      int br = brow0 + row;
      float4 bv = make_float4(0.f, 0.f, 0.f, 0.f);
      if (br < CAP) bv = *reinterpret_cast<const float4*>(&Bb[(size_t)br * KDIM + k0 + kq]);
      ushort4 pb = make_ushort4(f2bf(bv.x), f2bf(bv.y), f2bf(bv.z), f2bf(bv.w));
      *reinterpret_cast<ushort4*>(&lds_b[row * KPAD + kq]) = pb;
    }
    __syncthreads();

    bf16x8 af[4], bfr[4];
    #pragma unroll
    for (int m = 0; m < 4; ++m)
      af[m] = *reinterpret_cast<const bf16x8*>(&lds_a[(wr*64 + m*16 + lrow) * KPAD + lko]);
    #pragma unroll
    for (int n = 0; n < 4; ++n)
      bfr[n] = *reinterpret_cast<const bf16x8*>(&lds_b[(wc*64 + n*16 + lrow) * KPAD + lko]);

    #pragma unroll
    for (int m = 0; m < 4; ++m)
      #pragma unroll
      for (int n = 0; n < 4; ++n)
        acc[m][n] = __builtin_amdgcn_mfma_f32_16x16x32_bf16(af[m], bfr[n], acc[m][n], 0, 0, 0);
    __syncthreads();
  }

  #pragma unroll
  for (int m = 0; m < 4; ++m) {
    #pragma unroll
    for (int n = 0; n < 4; ++n) {
      int col  = wc*64 + n*16 + (lane & 15);
      int rowb = wr*64 + m*16 + (lane >> 4) * 4;
      #pragma unroll
      for (int r = 0; r < 4; ++r)
        sim[(rowb + r) * SIMPAD + col] = acc[m][n][r];
    }
  }
  __syncthreads();

  if (tid < 128) {
    float s[TOPK]; int c[TOPK];
    #pragma unroll
    for (int i = 0; i < TOPK; ++i) { s[i] = -INFINITY; c[i] = 0x7FFFFFFF; }
    for (int j = 0; j < 128; ++j) {
      int col = brow0 + j;
      if (col >= CAP) break;
      if (!s_valid[j]) continue;
      float v = sim[tid * SIMPAD + j];
      if (v > s[TOPK-1]) {
        int p = TOPK - 1;
        while (p > 0 && v > s[p-1]) { s[p] = s[p-1]; c[p] = c[p-1]; --p; }
        s[p] = v; c[p] = col;
      }
    }
    size_t base = ((size_t)(arow0 + tid) * NT + ct) * TOPK;
    #pragma unroll
    for (int i = 0; i < TOPK; ++i) { cand_s[base + i] = s[i]; cand_c[base + i] = c[i]; }
  }
}

// ---------------- K2: merge candidates -> top-32 -> exact fp64 rescore -> output ----------------
__global__ __launch_bounds__(256) void k_select(
    const float* __restrict__ Aq, const float* __restrict__ Bb,
    const float* __restrict__ content,
    const float* __restrict__ cand_s, const int* __restrict__ cand_c,
    float* __restrict__ out)
{
  __shared__ float  s_s[NCAND];
  __shared__ int    s_c[NCAND];
  __shared__ float  s_q[KDIM];
  __shared__ float  r_s[256];
  __shared__ int    r_c[256];
  __shared__ int    r_p[256];
  __shared__ int    sel_c[32];
  __shared__ double sel_v[32];
  __shared__ int    o_col[TOPK];
  __shared__ int    o_ok[TOPK];

  const int tid = threadIdx.x;
  const int b   = blockIdx.x;

  size_t cbase = (size_t)b * NCAND;
  for (int i = tid; i < NCAND; i += 256) { s_s[i] = cand_s[cbase + i]; s_c[i] = cand_c[cbase + i]; }
  for (int i = tid; i < KDIM; i += 256) s_q[i] = Aq[(size_t)b * KDIM + i];
  if (tid < TOPK) { o_ok[tid] = 0; o_col[tid] = 0; }
  __syncthreads();

  for (int k = 0; k < 32; ++k) {
    float best = -INFINITY; int bc = 0x7FFFFFFF; int bp = 0;
    for (int i = tid; i < NCAND; i += 256) {
      float v = s_s[i]; int cc = s_c[i];
      if (v > best || (v == best && cc < bc)) { best = v; bc = cc; bp = i; }
    }
    r_s[tid] = best; r_c[tid] = bc; r_p[tid] = bp;
    __syncthreads();
    for (int off = 128; off > 0; off >>= 1) {
      if (tid < off) {
        float v = r_s[tid + off]; int cc = r_c[tid + off];
        if (v > r_s[tid] || (v == r_s[tid] && cc < r_c[tid])) {
          r_s[tid] = v; r_c[tid] = cc; r_p[tid] = r_p[tid + off];
        }
      }
      __syncthreads();
    }
    if (tid == 0) { sel_c[k] = r_c[0]; s_s[r_p[0]] = -INFINITY; }
    __syncthreads();
  }

  const int wid = tid >> 6, lane = tid & 63;
  for (int q = 0; q < 8; ++q) {
    int i  = wid * 8 + q;
    int cc = sel_c[i];
    bool ok = (cc >= 0 && cc < CAP);
    double a = 0.0;
    if (ok) {
      const float* brow = &Bb[(size_t)cc * KDIM];
      #pragma unroll 4
      for (int j = 0; j < KDIM / 64; ++j) {
        int kk = j * 64 + lane;
        a += (double)s_q[kk] * (double)brow[kk];
      }
    }
    #pragma unroll
    for (int off = 32; off > 0; off >>= 1) a += __shfl_down(a, off);
    if (lane == 0) sel_v[i] = ok ? a : -INFINITY;
  }
  __syncthreads();

  if (tid < 32) {
    double my = sel_v[tid]; int mc = sel_c[tid];
    int rank = 0;
    for (int j = 0; j < 32; ++j) {
      double ov = sel_v[j]; int oc = sel_c[j];
      if (ov > my || (ov == my && (oc < mc || (oc == mc && j < tid)))) ++rank;
    }
    if (rank < TOPK) {
      double simv = my * (1.0 / 40.0);
      int pass = (my != -INFINITY) && (simv >= 0.3);
      out[(size_t)BQ * TOPK * CDIM + (size_t)b * TOPK + rank] = pass ? (float)simv : 0.0f;
      o_col[rank] = mc; o_ok[rank] = pass;
    }
  }
  __syncthreads();

  for (int idx = tid; idx < TOPK * CDIM; idx += 256) {
    int slot = idx / CDIM;
    int d    = idx - slot * CDIM;
    float v  = 0.f;
    if (o_ok[slot]) v = content[(size_t)o_col[slot] * CDIM + d];
    out[(size_t)b * TOPK * CDIM + idx] = v;
  }
}

extern "C" void kernel_launch(void* const* d_in, const int* in_sizes, int n_in,
                              void* d_out, int out_size, void* d_ws, size_t ws_size,
                              hipStream_t stream) {
  const float* q        = (const float*)d_in[0];
  const float* bank     = (const float*)d_in[1];
  const float* content  = (const float*)d_in[2];
  const int*   valid    = (const int*)d_in[3];
  float* out = (float*)d_out;

  if (ws_size >= WS_NEED) {
    unsigned short* Bbf = (unsigned short*)((char*)d_ws + WS_BBF);
    unsigned short* Abf = (unsigned short*)((char*)d_ws + WS_ABF);
    float* cand_s = (float*)((char*)d_ws + WS_CS);
    int*   cand_c = (int*)((char*)d_ws + WS_CC);

    k_cvt<<<dim3(4096), dim3(256), 0, stream>>>(bank, Bbf, CAP * KDIM / 8);
    k_cvt<<<dim3(512),  dim3(256), 0, stream>>>(q,    Abf, BQ * KDIM / 8);
    k_gemm_bf16<<<dim3(98 * 64), dim3(256), 0, stream>>>(Abf, Bbf, valid, cand_s, cand_c);
    k_select<<<dim3(BQ), dim3(256), 0, stream>>>(q, bank, content, cand_s, cand_c, out);
  } else {
    float* cand_s = (float*)d_ws;
    int*   cand_c = (int*)((char*)d_ws + (size_t)BQ * NCAND * 4);
    k_gemm_cand<<<dim3(MT * NT), dim3(256), 0, stream>>>(q, bank, valid, cand_s, cand_c);
    k_select<<<dim3(BQ), dim3(256), 0, stream>>>(q, bank, content, cand_s, cand_c, out);
  }
}

// Round 4
// 1236.025 us; speedup vs baseline: 2.4081x; 1.1717x over previous
//
#include <hip/hip_runtime.h>
#include <hip/hip_bf16.h>
#include <math.h>

#define BQ   1024
#define CAP  100000
#define KDIM 2048
#define CDIM 384
#define TOPK 5

// ---- legacy fallback (round-2 proven) tiling ----
#define MT   8
#define NT   782
#define NCAND (NT*TOPK)
#define KPAD 56
#define SIMPAD 129

// ---- 256x256 8-phase path ----
#define NT2  391            // ceil(100000/256); padded rows = 100096
#define NC2  (NT2*TOPK)     // 1955 candidates/row
#define NKT  32             // K-tiles of 64 (K=2048)
#define RSC  16             // rescore set size

// ws layout (bytes) for the 8-phase path
#define WS2_B    0UL
#define WS2_A    409993216UL   // 391 tiles * 1048576
#define WS2_CS   414187520UL   // + 4 tiles  * 1048576
#define WS2_CC   422195200UL   // + 1024*1955*4
#define WS2_NEED 430202880UL   // + 1024*1955*4

typedef __bf16 bf16x8 __attribute__((ext_vector_type(8)));
typedef float  f32x4  __attribute__((ext_vector_type(4)));
typedef unsigned short ushort8 __attribute__((ext_vector_type(8)));

__device__ __forceinline__ unsigned short f2bf(float f) {
  unsigned int u = __float_as_uint(f);
  u += 0x7FFF + ((u >> 16) & 1);   // RNE
  return (unsigned short)(u >> 16);
}

// ---------------- K0: fp32 -> bf16 into pre-tiled + pre-swizzled global layout --------------
// Layout per 256-row tile (1,048,576 B): [kt 0..31][half 0..1][16KB half-tile],
// half-tile = 16 subtiles of 1024B: [rg 0..7][cg 0..1]; subtile byte = lr*64 + lcb,
// where stored lcb is the st_16x32-XOR'd position: logical chunk = stored ^ ((lr>>3&1)<<1).
__global__ __launch_bounds__(256) void k_cvt256(const float* __restrict__ src,
                                                unsigned short* __restrict__ dst,
                                                int nchunks, int nrows) {
  int stride = gridDim.x * 256;
  for (int g = blockIdx.x * 256 + threadIdx.x; g < nchunks; g += stride) {
    int tile = g >> 16;          // 65536 16B-chunks per tile
    int rem  = g & 65535;
    int kt   = rem >> 11;        // 2048 chunks per K-tile
    int rem2 = rem & 2047;
    int h    = rem2 >> 10;       // half (128 rows)
    int p16  = rem2 & 1023;      // chunk within 16KB half
    int st   = p16 >> 6;         // 1024B subtile
    int loc  = p16 & 63;
    int lr   = loc >> 2;         // row within subtile
    int lc16 = loc & 3;          // stored 16B slot
    int lcl  = lc16 ^ (((lr >> 3) & 1) << 1);   // logical 16B slot (XOR involution)
    int rg = st >> 1, cg = st & 1;
    int row = h * 128 + rg * 16 + lr;
    int col = cg * 32 + lcl * 8;
    int srcRow = tile * 256 + row;
    ushort8 o = {0,0,0,0,0,0,0,0};
    if (srcRow < nrows) {
      const float* sp = src + (size_t)srcRow * KDIM + kt * 64 + col;
      float4 a = *reinterpret_cast<const float4*>(sp);
      float4 b = *reinterpret_cast<const float4*>(sp + 4);
      o[0]=f2bf(a.x); o[1]=f2bf(a.y); o[2]=f2bf(a.z); o[3]=f2bf(a.w);
      o[4]=f2bf(b.x); o[5]=f2bf(b.y); o[6]=f2bf(b.z); o[7]=f2bf(b.w);
    }
    *reinterpret_cast<ushort8*>(dst + (size_t)g * 8) = o;
  }
}

// ---------------- K1: 256x256 8-phase BK=64 GEMM + per-(row,256-coltile) top-5 --------------
__global__ __launch_bounds__(512, 2) void k_gemm8(
    const unsigned short* __restrict__ At, const unsigned short* __restrict__ Bt,
    const int* __restrict__ valid,
    float* __restrict__ cand_s, int* __restrict__ cand_c)
{
  __shared__ __align__(16) unsigned short smem[65536];   // 128KB: buf c at c*32768 us (A 16K us, B 16K us)
  __shared__ int   s_valid[256];
  __shared__ float mg_s[256][TOPK];
  __shared__ int   mg_c[256][TOPK];

  const int tid = threadIdx.x;
  // bijective XCD-chunked swizzle (nwg=1564, q=195, r=4): same-ct blocks share an XCD
  int xcd = blockIdx.x & 7, pos = blockIdx.x >> 3;
  int wg = (xcd < 4) ? (xcd * 196 + pos) : (784 + (xcd - 4) * 195 + pos);
  const int rt = wg & 3, ct = wg >> 2;

  const int lane = tid & 63, wid = tid >> 6;
  const int wm = wid >> 2, wn = wid & 3;     // 2M x 4N waves
  const int lrow = lane & 15;
  const int swzus = ((lane >> 4) * 8) ^ (((lrow >> 3) & 1) << 4);   // ushort units

  if (tid < 256) s_valid[tid] = (ct * 256 + tid < CAP) ? valid[ct * 256 + tid] : 0;

  const unsigned short* gA = At + (size_t)rt * 524288;   // 1MB tiles (us units)
  const unsigned short* gB = Bt + (size_t)ct * 524288;

  // frag base offsets (us) within a dbuf
  const int abase = wm * 8192 + lrow * 32 + swzus;                       // + (m*2+kk)*512
  const int bbase = 16384 + (wn >> 1) * 8192 + (wn & 1) * 4096 + lrow * 32 + swzus; // + (n*2+kk)*512

  // stage one half-tile (2 x global_load_lds dwordx4 per thread)
  auto STG = [&](const unsigned short* g, int lbase, int t, int h) {
    #pragma unroll
    for (int j = 0; j < 2; ++j) {
      const unsigned short* s = g + t * 16384 + h * 8192 + j * 4096 + tid * 8;
      unsigned short* d = smem + lbase + h * 8192 + j * 4096 + wid * 512;
      __builtin_amdgcn_global_load_lds(
          (const __attribute__((address_space(1))) unsigned int*)s,
          (__attribute__((address_space(3))) unsigned int*)d, 16, 0, 0);
    }
  };

  f32x4 acc[8][4];
  const f32x4 z4 = {0.f,0.f,0.f,0.f};
  #pragma unroll
  for (int m = 0; m < 8; ++m)
    #pragma unroll
    for (int n = 0; n < 4; ++n) acc[m][n] = z4;

  // prologue: tau=0 all 4 half-tiles; tau=1: B0, A0  (issue order matters for vmcnt audit)
  STG(gB, 16384, 0, 0); STG(gB, 16384, 0, 1);
  STG(gA, 0,     0, 0); STG(gA, 0,     0, 1);
  STG(gB, 32768 + 16384, 1, 0);
  STG(gA, 32768,         1, 0);
  asm volatile("s_waitcnt vmcnt(4)" ::: "memory");   // tau=0 landed; B0(1),A0(1) in flight
  __builtin_amdgcn_s_barrier();

  bf16x8 af[8][2], bfr[4][2];

  #pragma unroll 2
  for (int t = 0; t < NKT; ++t) {
    const int cb = (t & 1) * 32768, ob = cb ^ 32768;
    // ---- phase 1: read all B frags + A m0,1; stage B1,A1(t+1) -> other buf
    #pragma unroll
    for (int n = 0; n < 4; ++n)
      #pragma unroll
      for (int kk = 0; kk < 2; ++kk)
        bfr[n][kk] = *reinterpret_cast<const bf16x8*>(&smem[cb + bbase + (n*2+kk)*512]);
    #pragma unroll
    for (int m = 0; m < 2; ++m)
      #pragma unroll
      for (int kk = 0; kk < 2; ++kk)
        af[m][kk] = *reinterpret_cast<const bf16x8*>(&smem[cb + abase + (m*2+kk)*512]);
    if (t + 1 < NKT) { STG(gB, ob + 16384, t+1, 1); STG(gA, ob, t+1, 1); }
    __builtin_amdgcn_s_barrier();
    asm volatile("s_waitcnt lgkmcnt(0)" ::: "memory");
    __builtin_amdgcn_s_setprio(1);
    #pragma unroll
    for (int m = 0; m < 2; ++m)
      #pragma unroll
      for (int kk = 0; kk < 2; ++kk)
        #pragma unroll
        for (int n = 0; n < 4; ++n)
          acc[m][n] = __builtin_amdgcn_mfma_f32_16x16x32_bf16(af[m][kk], bfr[n][kk], acc[m][n], 0,0,0);
    __builtin_amdgcn_s_setprio(0);
    __builtin_amdgcn_s_barrier();
    // ---- phase 2: read A m2..5; stage B0(t+2) -> cur buf
    #pragma unroll
    for (int m = 2; m < 6; ++m)
      #pragma unroll
      for (int kk = 0; kk < 2; ++kk)
        af[m][kk] = *reinterpret_cast<const bf16x8*>(&smem[cb + abase + (m*2+kk)*512]);
    if (t + 2 < NKT) STG(gB, cb + 16384, t+2, 0);
    __builtin_amdgcn_s_barrier();
    asm volatile("s_waitcnt lgkmcnt(0)" ::: "memory");
    __builtin_amdgcn_s_setprio(1);
    #pragma unroll
    for (int m = 2; m < 4; ++m)
      #pragma unroll
      for (int kk = 0; kk < 2; ++kk)
        #pragma unroll
        for (int n = 0; n < 4; ++n)
          acc[m][n] = __builtin_amdgcn_mfma_f32_16x16x32_bf16(af[m][kk], bfr[n][kk], acc[m][n], 0,0,0);
    __builtin_amdgcn_s_setprio(0);
    __builtin_amdgcn_s_barrier();
    // ---- phase 3: read A m6,7
    #pragma unroll
    for (int m = 6; m < 8; ++m)
      #pragma unroll
      for (int kk = 0; kk < 2; ++kk)
        af[m][kk] = *reinterpret_cast<const bf16x8*>(&smem[cb + abase + (m*2+kk)*512]);
    __builtin_amdgcn_s_barrier();
    asm volatile("s_waitcnt lgkmcnt(0)" ::: "memory");
    __builtin_amdgcn_s_setprio(1);
    #pragma unroll
    for (int m = 4; m < 6; ++m)
      #pragma unroll
      for (int kk = 0; kk < 2; ++kk)
        #pragma unroll
        for (int n = 0; n < 4; ++n)
          acc[m][n] = __builtin_amdgcn_mfma_f32_16x16x32_bf16(af[m][kk], bfr[n][kk], acc[m][n], 0,0,0);
    __builtin_amdgcn_s_setprio(0);
    __builtin_amdgcn_s_barrier();
    // ---- phase 4: stage A0(t+2) -> cur buf; counted vmcnt; compute m6,7
    if (t + 2 < NKT) {
      STG(gA, cb, t+2, 0);
      asm volatile("s_waitcnt vmcnt(4)" ::: "memory");
    } else {
      asm volatile("s_waitcnt vmcnt(0)" ::: "memory");
    }
    __builtin_amdgcn_s_barrier();
    __builtin_amdgcn_s_setprio(1);
    #pragma unroll
    for (int m = 6; m < 8; ++m)
      #pragma unroll
      for (int kk = 0; kk < 2; ++kk)
        #pragma unroll
        for (int n = 0; n < 4; ++n)
          acc[m][n] = __builtin_amdgcn_mfma_f32_16x16x32_bf16(af[m][kk], bfr[n][kk], acc[m][n], 0,0,0);
    __builtin_amdgcn_s_setprio(0);
    __builtin_amdgcn_s_barrier();
  }

  // ---- epilogue: stream sim through XOR-swizzled [256][128] f32 slab, per-row top-5 ----
  float* simf = (float*)smem;
  float ts[TOPK]; int tc[TOPK];
  #pragma unroll
  for (int i = 0; i < TOPK; ++i) { ts[i] = -INFINITY; tc[i] = 0x7FFFFFFF; }
  const int qrow0 = rt * 256;

  #pragma unroll
  for (int h2 = 0; h2 < 2; ++h2) {
    __syncthreads();
    if ((wn >> 1) == h2) {
      #pragma unroll
      for (int m = 0; m < 8; ++m)
        #pragma unroll
        for (int n = 0; n < 4; ++n) {
          int colc = (wn & 1) * 64 + n * 16 + lrow;
          #pragma unroll
          for (int r = 0; r < 4; ++r) {
            int row = wm * 128 + m * 16 + (lane >> 4) * 4 + r;
            simf[row * 128 + (colc ^ (row & 127))] = acc[m][n][r];
          }
        }
    }
    __syncthreads();
    int row = tid >> 1, sub = tid & 1;
    #pragma unroll 4
    for (int j = 0; j < 64; ++j) {
      int colc = sub * 64 + j;
      float v = simf[row * 128 + (colc ^ (row & 127))];
      int cg2 = h2 * 128 + colc;
      if (s_valid[cg2] && v > ts[TOPK-1]) {
        int col = ct * 256 + cg2;
        int p = TOPK - 1;
        while (p > 0 && v > ts[p-1]) { ts[p] = ts[p-1]; tc[p] = tc[p-1]; --p; }
        ts[p] = v; tc[p] = col;
      }
    }
  }
  __syncthreads();
  {
    int row = tid >> 1;
    if (tid & 1) {
      #pragma unroll
      for (int i = 0; i < TOPK; ++i) { mg_s[row][i] = ts[i]; mg_c[row][i] = tc[i]; }
    }
    __syncthreads();
    if (!(tid & 1)) {
      float os[TOPK]; int oc[TOPK]; int i0 = 0, i1 = 0;
      #pragma unroll
      for (int k = 0; k < TOPK; ++k) {
        float v1 = mg_s[row][i1];
        if (ts[i0] >= v1) { os[k] = ts[i0]; oc[k] = tc[i0]; ++i0; }
        else              { os[k] = v1;     oc[k] = mg_c[row][i1]; ++i1; }
      }
      size_t base = ((size_t)(qrow0 + row) * NT2 + ct) * TOPK;
      #pragma unroll
      for (int i = 0; i < TOPK; ++i) { cand_s[base + i] = os[i]; cand_c[base + i] = oc[i]; }
    }
  }
}

// ---------------- K2: merge 1955 candidates -> top-16 -> exact fp64 rescore -> output --------
__global__ __launch_bounds__(256) void k_select16(
    const float* __restrict__ Aq, const float* __restrict__ Bb,
    const float* __restrict__ content,
    const float* __restrict__ cand_s, const int* __restrict__ cand_c,
    float* __restrict__ out)
{
  __shared__ float  s_s[NC2];
  __shared__ int    s_c[NC2];
  __shared__ float  s_q[KDIM];
  __shared__ float  w_v[4]; __shared__ int w_c[4], w_p[4];
  __shared__ int    sel_c[RSC];
  __shared__ double sel_v[RSC];
  __shared__ int    o_col[TOPK], o_ok[TOPK];

  const int tid = threadIdx.x;
  const int b   = blockIdx.x;
  const int wid = tid >> 6, lane = tid & 63;

  size_t cbase = (size_t)b * NC2;
  for (int i = tid; i < NC2; i += 256) { s_s[i] = cand_s[cbase + i]; s_c[i] = cand_c[cbase + i]; }
  for (int i = tid; i < KDIM; i += 256) s_q[i] = Aq[(size_t)b * KDIM + i];
  if (tid < TOPK) { o_ok[tid] = 0; o_col[tid] = 0; }
  __syncthreads();

  // 16 x argmax (tie -> lowest col), wave-shuffle reduce
  for (int k = 0; k < RSC; ++k) {
    float best = -INFINITY; int bc = 0x7FFFFFFF; int bp = 0;
    for (int i = tid; i < NC2; i += 256) {
      float v = s_s[i]; int cc = s_c[i];
      if (v > best || (v == best && cc < bc)) { best = v; bc = cc; bp = i; }
    }
    #pragma unroll
    for (int off = 32; off > 0; off >>= 1) {
      float v2 = __shfl_xor(best, off); int c2 = __shfl_xor(bc, off); int p2 = __shfl_xor(bp, off);
      if (v2 > best || (v2 == best && c2 < bc)) { best = v2; bc = c2; bp = p2; }
    }
    if (lane == 0) { w_v[wid] = best; w_c[wid] = bc; w_p[wid] = bp; }
    __syncthreads();
    if (tid == 0) {
      float bv = w_v[0]; int bcc = w_c[0], bpp = w_p[0];
      #pragma unroll
      for (int w = 1; w < 4; ++w) {
        if (w_v[w] > bv || (w_v[w] == bv && w_c[w] < bcc)) { bv = w_v[w]; bcc = w_c[w]; bpp = w_p[w]; }
      }
      sel_c[k] = bcc; s_s[bpp] = -INFINITY;
    }
    __syncthreads();
  }

  // exact fp64 rescore: 4 waves x 4 candidates
  for (int q = 0; q < 4; ++q) {
    int i  = wid * 4 + q;
    int cc = sel_c[i];
    bool ok = (cc >= 0 && cc < CAP);
    double a = 0.0;
    if (ok) {
      const float* brow = &Bb[(size_t)cc * KDIM];
      #pragma unroll 4
      for (int j = 0; j < KDIM / 64; ++j) {
        int kk = j * 64 + lane;
        a += (double)s_q[kk] * (double)brow[kk];
      }
    }
    #pragma unroll
    for (int off = 32; off > 0; off >>= 1) a += __shfl_down(a, off);
    if (lane == 0) sel_v[i] = ok ? a : -INFINITY;
  }
  __syncthreads();

  // exact ranking of the 16 (score desc, col asc, position asc), emit top-5
  if (tid < RSC) {
    double my = sel_v[tid]; int mc = sel_c[tid];
    int rank = 0;
    for (int j = 0; j < RSC; ++j) {
      double ov = sel_v[j]; int oc = sel_c[j];
      if (ov > my || (ov == my && (oc < mc || (oc == mc && j < tid)))) ++rank;
    }
    if (rank < TOPK) {
      double simv = my * (1.0 / 40.0);
      int pass = (my != -INFINITY) && (simv >= 0.3);
      out[(size_t)BQ * TOPK * CDIM + (size_t)b * TOPK + rank] = pass ? (float)simv : 0.0f;
      o_col[rank] = mc; o_ok[rank] = pass;
    }
  }
  __syncthreads();

  for (int idx = tid; idx < TOPK * CDIM; idx += 256) {
    int slot = idx / CDIM;
    int d    = idx - slot * CDIM;
    float v  = 0.f;
    if (o_ok[slot]) v = content[(size_t)o_col[slot] * CDIM + d];
    out[(size_t)b * TOPK * CDIM + idx] = v;
  }
}

// ---------------- fallback: round-2 proven fp32 path ----------------
__global__ __launch_bounds__(256) void k_gemm_cand(
    const float* __restrict__ Aq, const float* __restrict__ Bb,
    const int* __restrict__ valid,
    float* __restrict__ cand_s, int* __restrict__ cand_c)
{
  __shared__ __align__(16) unsigned char smem[128*SIMPAD*4];
  __shared__ int s_valid[128];
  unsigned short* lds_a = (unsigned short*)smem;
  unsigned short* lds_b = lds_a + 128*KPAD;
  float* sim = (float*)smem;

  const int tid = threadIdx.x;
  const int bid = blockIdx.x;
  const int rt = bid & 7;
  const int ct = bid >> 3;
  const int lane = tid & 63;
  const int wid  = tid >> 6;
  const int wr = wid >> 1;
  const int wc = wid & 1;
  const int lrow = lane & 15;
  const int lko  = (lane >> 4) * 8;

  const int arow0 = rt * 128;
  const int brow0 = ct * 128;

  if (tid < 128) {
    int col = brow0 + tid;
    s_valid[tid] = (col < CAP) ? valid[col] : 0;
  }

  f32x4 acc[4][4];
  const f32x4 zero4 = {0.f, 0.f, 0.f, 0.f};
  #pragma unroll
  for (int m = 0; m < 4; ++m)
    #pragma unroll
    for (int n = 0; n < 4; ++n) acc[m][n] = zero4;

  for (int k0 = 0; k0 < KDIM; k0 += 32) {
    #pragma unroll
    for (int it = 0; it < 4; ++it) {
      int idx = it * 256 + tid;
      int row = idx >> 3;
      int kq  = (idx & 7) * 4;
      float4 av = *reinterpret_cast<const float4*>(&Aq[(size_t)(arow0 + row) * KDIM + k0 + kq]);
      ushort4 pa = make_ushort4(f2bf(av.x), f2bf(av.y), f2bf(av.z), f2bf(av.w));
      *reinterpret_cast<ushort4*>(&lds_a[row * KPAD + kq]) = pa;
      int br = brow0 + row;
      float4 bv = make_float4(0.f, 0.f, 0.f, 0.f);
      if (br < CAP) bv = *reinterpret_cast<const float4*>(&Bb[(size_t)br * KDIM + k0 + kq]);
      ushort4 pb = make_ushort4(f2bf(bv.x), f2bf(bv.y), f2bf(bv.z), f2bf(bv.w));
      *reinterpret_cast<ushort4*>(&lds_b[row * KPAD + kq]) = pb;
    }
    __syncthreads();

    bf16x8 af2[4], bf2[4];
    #pragma unroll
    for (int m = 0; m < 4; ++m)
      af2[m] = *reinterpret_cast<const bf16x8*>(&lds_a[(wr*64 + m*16 + lrow) * KPAD + lko]);
    #pragma unroll
    for (int n = 0; n < 4; ++n)
      bf2[n] = *reinterpret_cast<const bf16x8*>(&lds_b[(wc*64 + n*16 + lrow) * KPAD + lko]);

    #pragma unroll
    for (int m = 0; m < 4; ++m)
      #pragma unroll
      for (int n = 0; n < 4; ++n)
        acc[m][n] = __builtin_amdgcn_mfma_f32_16x16x32_bf16(af2[m], bf2[n], acc[m][n], 0, 0, 0);
    __syncthreads();
  }

  #pragma unroll
  for (int m = 0; m < 4; ++m) {
    #pragma unroll
    for (int n = 0; n < 4; ++n) {
      int col  = wc*64 + n*16 + (lane & 15);
      int rowb = wr*64 + m*16 + (lane >> 4) * 4;
      #pragma unroll
      for (int r = 0; r < 4; ++r)
        sim[(rowb + r) * SIMPAD + col] = acc[m][n][r];
    }
  }
  __syncthreads();

  if (tid < 128) {
    float s[TOPK]; int c[TOPK];
    #pragma unroll
    for (int i = 0; i < TOPK; ++i) { s[i] = -INFINITY; c[i] = 0x7FFFFFFF; }
    for (int j = 0; j < 128; ++j) {
      int col = brow0 + j;
      if (col >= CAP) break;
      if (!s_valid[j]) continue;
      float v = sim[tid * SIMPAD + j];
      if (v > s[TOPK-1]) {
        int p = TOPK - 1;
        while (p > 0 && v > s[p-1]) { s[p] = s[p-1]; c[p] = c[p-1]; --p; }
        s[p] = v; c[p] = col;
      }
    }
    size_t base = ((size_t)(arow0 + tid) * NT + ct) * TOPK;
    #pragma unroll
    for (int i = 0; i < TOPK; ++i) { cand_s[base + i] = s[i]; cand_c[base + i] = c[i]; }
  }
}

__global__ __launch_bounds__(256) void k_select(
    const float* __restrict__ Aq, const float* __restrict__ Bb,
    const float* __restrict__ content,
    const float* __restrict__ cand_s, const int* __restrict__ cand_c,
    float* __restrict__ out)
{
  __shared__ float  s_s[NCAND];
  __shared__ int    s_c[NCAND];
  __shared__ float  s_q[KDIM];
  __shared__ float  r_s[256];
  __shared__ int    r_c[256];
  __shared__ int    r_p[256];
  __shared__ int    sel_c[32];
  __shared__ double sel_v[32];
  __shared__ int    o_col[TOPK];
  __shared__ int    o_ok[TOPK];

  const int tid = threadIdx.x;
  const int b   = blockIdx.x;

  size_t cbase = (size_t)b * NCAND;
  for (int i = tid; i < NCAND; i += 256) { s_s[i] = cand_s[cbase + i]; s_c[i] = cand_c[cbase + i]; }
  for (int i = tid; i < KDIM; i += 256) s_q[i] = Aq[(size_t)b * KDIM + i];
  if (tid < TOPK) { o_ok[tid] = 0; o_col[tid] = 0; }
  __syncthreads();

  for (int k = 0; k < 32; ++k) {
    float best = -INFINITY; int bc = 0x7FFFFFFF; int bp = 0;
    for (int i = tid; i < NCAND; i += 256) {
      float v = s_s[i]; int cc = s_c[i];
      if (v > best || (v == best && cc < bc)) { best = v; bc = cc; bp = i; }
    }
    r_s[tid] = best; r_c[tid] = bc; r_p[tid] = bp;
    __syncthreads();
    for (int off = 128; off > 0; off >>= 1) {
      if (tid < off) {
        float v = r_s[tid + off]; int cc = r_c[tid + off];
        if (v > r_s[tid] || (v == r_s[tid] && cc < r_c[tid])) {
          r_s[tid] = v; r_c[tid] = cc; r_p[tid] = r_p[tid + off];
        }
      }
      __syncthreads();
    }
    if (tid == 0) { sel_c[k] = r_c[0]; s_s[r_p[0]] = -INFINITY; }
    __syncthreads();
  }

  const int wid = tid >> 6, lane = tid & 63;
  for (int q = 0; q < 8; ++q) {
    int i  = wid * 8 + q;
    int cc = sel_c[i];
    bool ok = (cc >= 0 && cc < CAP);
    double a = 0.0;
    if (ok) {
      const float* brow = &Bb[(size_t)cc * KDIM];
      #pragma unroll 4
      for (int j = 0; j < KDIM / 64; ++j) {
        int kk = j * 64 + lane;
        a += (double)s_q[kk] * (double)brow[kk];
      }
    }
    #pragma unroll
    for (int off = 32; off > 0; off >>= 1) a += __shfl_down(a, off);
    if (lane == 0) sel_v[i] = ok ? a : -INFINITY;
  }
  __syncthreads();

  if (tid < 32) {
    double my = sel_v[tid]; int mc = sel_c[tid];
    int rank = 0;
    for (int j = 0; j < 32; ++j) {
      double ov = sel_v[j]; int oc = sel_c[j];
      if (ov > my || (ov == my && (oc < mc || (oc == mc && j < tid)))) ++rank;
    }
    if (rank < TOPK) {
      double simv = my * (1.0 / 40.0);
      int pass = (my != -INFINITY) && (simv >= 0.3);
      out[(size_t)BQ * TOPK * CDIM + (size_t)b * TOPK + rank] = pass ? (float)simv : 0.0f;
      o_col[rank] = mc; o_ok[rank] = pass;
    }
  }
  __syncthreads();

  for (int idx = tid; idx < TOPK * CDIM; idx += 256) {
    int slot = idx / CDIM;
    int d    = idx - slot * CDIM;
    float v  = 0.f;
    if (o_ok[slot]) v = content[(size_t)o_col[slot] * CDIM + d];
    out[(size_t)b * TOPK * CDIM + idx] = v;
  }
}

extern "C" void kernel_launch(void* const* d_in, const int* in_sizes, int n_in,
                              void* d_out, int out_size, void* d_ws, size_t ws_size,
                              hipStream_t stream) {
  const float* q        = (const float*)d_in[0];
  const float* bank     = (const float*)d_in[1];
  const float* content  = (const float*)d_in[2];
  const int*   valid    = (const int*)d_in[3];
  float* out = (float*)d_out;

  if (ws_size >= WS2_NEED) {
    unsigned short* Bt = (unsigned short*)((char*)d_ws + WS2_B);
    unsigned short* At = (unsigned short*)((char*)d_ws + WS2_A);
    float* cand_s = (float*)((char*)d_ws + WS2_CS);
    int*   cand_c = (int*)((char*)d_ws + WS2_CC);

    k_cvt256<<<dim3(4096), dim3(256), 0, stream>>>(bank, Bt, NT2 * 65536, CAP);
    k_cvt256<<<dim3(1024), dim3(256), 0, stream>>>(q,    At, 4 * 65536, BQ);
    k_gemm8<<<dim3(1564), dim3(512), 0, stream>>>(At, Bt, valid, cand_s, cand_c);
    k_select16<<<dim3(BQ), dim3(256), 0, stream>>>(q, bank, content, cand_s, cand_c, out);
  } else {
    float* cand_s = (float*)d_ws;
    int*   cand_c = (int*)((char*)d_ws + (size_t)BQ * NCAND * 4);
    k_gemm_cand<<<dim3(MT * NT), dim3(256), 0, stream>>>(q, bank, valid, cand_s, cand_c);
    k_select<<<dim3(BQ), dim3(256), 0, stream>>>(q, bank, content, cand_s, cand_c, out);
  }
}

// Round 5
// 1006.387 us; speedup vs baseline: 2.9576x; 1.2282x over previous
//
#include <hip/hip_runtime.h>
#include <hip/hip_bf16.h>
#include <math.h>
#include <limits.h>

#define BQ   1024
#define CAP  100000
#define KDIM 2048
#define CDIM 384
#define TOPK 5
#define MT   8
#define NT   782            // ceil(100000/128)
#define NCAND (NT*TOPK)     // 3910
#define RSC  32             // rescore set size
// fallback (round-2 proven) params
#define KPAD 56
#define SIMPAD 129

// i8 path ws layout (bytes)
#define WSI_B    0UL            // 782 tiles * 262144 = 205,000,704
#define WSI_A    205000704UL    // 8 tiles * 262144   = 2,097,152
#define WSI_CV   207097856UL    // 1024*3910*4
#define WSI_CC   223113216UL    // 1024*3910*4
#define WSI_NEED 239128576UL

typedef int    int4v  __attribute__((ext_vector_type(4)));
typedef float  f32x4  __attribute__((ext_vector_type(4)));
typedef __bf16 bf16x8 __attribute__((ext_vector_type(8)));

__device__ __forceinline__ unsigned short f2bf(float f) {
  unsigned int u = __float_as_uint(f);
  u += 0x7FFF + ((u >> 16) & 1);
  return (unsigned short)(u >> 16);
}

// ---------------- K0: fp32 -> i8 (x127) into tiled+chunk-XOR'd layout ----------------
// Per 128-row tile (262144 B): [kt 0..31][row 0..127][stored-chunk 0..3][16 B].
// stored chunk sc holds logical chunk lc = sc ^ ((row>>1)&3)  (XOR involution).
__global__ __launch_bounds__(256) void k_cvt_i8(const float* __restrict__ src,
                                                unsigned char* __restrict__ dst,
                                                int nchunks, int nrows) {
  int stride = gridDim.x * 256;
  for (int g = blockIdx.x * 256 + threadIdx.x; g < nchunks; g += stride) {
    int tile = g >> 14;          // 16384 16B-chunks per tile
    int rem  = g & 16383;
    int kt   = rem >> 9;         // 512 chunks per K-tile (128 rows x 4)
    int loc  = rem & 511;
    int row  = loc >> 2;
    int sc   = loc & 3;
    int lc   = sc ^ ((row >> 1) & 3);
    int srcRow = tile * 128 + row;
    unsigned int w0 = 0, w1 = 0, w2 = 0, w3 = 0;
    if (srcRow < nrows) {
      const float* sp = src + (size_t)srcRow * KDIM + kt * 64 + lc * 16;
      float4 a = *reinterpret_cast<const float4*>(sp);
      float4 b = *reinterpret_cast<const float4*>(sp + 4);
      float4 c = *reinterpret_cast<const float4*>(sp + 8);
      float4 d = *reinterpret_cast<const float4*>(sp + 12);
      #define Q8(x) ((unsigned int)(int)((x) * 127.f + 0.5f))
      w0 = Q8(a.x) | (Q8(a.y) << 8) | (Q8(a.z) << 16) | (Q8(a.w) << 24);
      w1 = Q8(b.x) | (Q8(b.y) << 8) | (Q8(b.z) << 16) | (Q8(b.w) << 24);
      w2 = Q8(c.x) | (Q8(c.y) << 8) | (Q8(c.z) << 16) | (Q8(c.w) << 24);
      w3 = Q8(d.x) | (Q8(d.y) << 8) | (Q8(d.z) << 16) | (Q8(d.w) << 24);
      #undef Q8
    }
    *reinterpret_cast<uint4*>(dst + (size_t)g * 16) = make_uint4(w0, w1, w2, w3);
  }
}

// ---------------- K1: i8 MFMA GEMM (m97-style 2-barrier loop) + per-(row,coltile) top-5 ----
__global__ __launch_bounds__(256) void k_gemm_i8(
    const unsigned char* __restrict__ At, const unsigned char* __restrict__ Bt,
    const int* __restrict__ valid,
    int* __restrict__ cand_v, int* __restrict__ cand_c)
{
  // union: staging (A 8KB + B 8KB i8) | sim chunk [128][33] i32 (16896 B)
  __shared__ __align__(16) unsigned char smem[16896];
  __shared__ int s_valid[128];
  unsigned char* lds_a = smem;          // [128][64] i8 (chunk-XOR'd)
  unsigned char* lds_b = smem + 8192;
  int* sim = (int*)smem;                // [128][33]

  const int bid = blockIdx.x;
  const int g = bid >> 6, sub = bid & 63;
  const int rt = sub >> 3;
  const int ct = g * 8 + (sub & 7);     // bid%8 == ct%8 -> B-tile sharers on one XCD
  if (ct >= NT) return;

  const int tid = threadIdx.x;
  const int lane = tid & 63;
  const int w    = tid >> 6;
  const int wr = w >> 1, wc = w & 1;
  const int lrow = lane & 15;
  // stored-chunk byte offset for this lane's K-chunk (XOR involution, lane-only)
  const int swc = (((lane >> 4) ^ ((lrow >> 1) & 3)) << 4);

  const int arow0 = rt * 128, brow0 = ct * 128;
  if (tid < 128) s_valid[tid] = (brow0 + tid < CAP) ? valid[brow0 + tid] : 0;

  int4v acc[4][4];
  const int4v z4 = {0, 0, 0, 0};
  #pragma unroll
  for (int m = 0; m < 4; ++m)
    #pragma unroll
    for (int n = 0; n < 4; ++n) acc[m][n] = z4;

  const unsigned char* gAt = At + (size_t)rt * 262144;
  const unsigned char* gBt = Bt + (size_t)ct * 262144;

  for (int kt = 0; kt < 32; ++kt) {
    #pragma unroll
    for (int j = 0; j < 2; ++j) {
      const unsigned char* sA = gAt + kt * 8192 + j * 4096 + tid * 16;
      unsigned char* dA = lds_a + j * 4096 + w * 1024;    // wave-uniform base
      __builtin_amdgcn_global_load_lds(
          (const __attribute__((address_space(1))) unsigned int*)sA,
          (__attribute__((address_space(3))) unsigned int*)dA, 16, 0, 0);
      const unsigned char* sB = gBt + kt * 8192 + j * 4096 + tid * 16;
      unsigned char* dB = lds_b + j * 4096 + w * 1024;
      __builtin_amdgcn_global_load_lds(
          (const __attribute__((address_space(1))) unsigned int*)sB,
          (__attribute__((address_space(3))) unsigned int*)dB, 16, 0, 0);
    }
    __syncthreads();

    int4v af[4], bfr[4];
    #pragma unroll
    for (int m = 0; m < 4; ++m)
      af[m] = *reinterpret_cast<const int4v*>(lds_a + (wr*64 + m*16 + lrow) * 64 + swc);
    #pragma unroll
    for (int n = 0; n < 4; ++n)
      bfr[n] = *reinterpret_cast<const int4v*>(lds_b + (wc*64 + n*16 + lrow) * 64 + swc);

    #pragma unroll
    for (int m = 0; m < 4; ++m)
      #pragma unroll
      for (int n = 0; n < 4; ++n)
        acc[m][n] = __builtin_amdgcn_mfma_i32_16x16x64_i8(af[m], bfr[n], acc[m][n], 0, 0, 0);
    __syncthreads();
  }

  // epilogue: 4 chunks of 32 cols via [128][33] i32 slab; running top-5 in regs
  int ts[TOPK]; int tc[TOPK];
  #pragma unroll
  for (int i = 0; i < TOPK; ++i) { ts[i] = INT_MIN; tc[i] = 0x7FFFFFFF; }

  for (int c = 0; c < 4; ++c) {
    __syncthreads();
    if (wc == (c >> 1)) {
      #pragma unroll
      for (int m = 0; m < 4; ++m) {
        #pragma unroll
        for (int nn = 0; nn < 2; ++nn) {
          int n = (c & 1) * 2 + nn;
          int rowb = wr*64 + m*16 + (lane >> 4) * 4;
          int lcol = nn*16 + lrow;
          #pragma unroll
          for (int r = 0; r < 4; ++r)
            sim[(rowb + r) * 33 + lcol] = acc[m][n][r];
        }
      }
    }
    __syncthreads();
    if (tid < 128) {
      #pragma unroll 4
      for (int j = 0; j < 32; ++j) {
        int jj = c * 32 + j;
        int v = sim[tid * 33 + j];
        if (s_valid[jj] && v > ts[TOPK-1]) {
          int col = brow0 + jj;
          int p = TOPK - 1;
          while (p > 0 && v > ts[p-1]) { ts[p] = ts[p-1]; tc[p] = tc[p-1]; --p; }
          ts[p] = v; tc[p] = col;
        }
      }
    }
  }

  if (tid < 128) {
    size_t base = ((size_t)(arow0 + tid) * NT + ct) * TOPK;
    #pragma unroll
    for (int i = 0; i < TOPK; ++i) { cand_v[base + i] = ts[i]; cand_c[base + i] = tc[i]; }
  }
}

// ---------------- K2: merge int candidates -> top-32 -> exact fp64 rescore -> output --------
__global__ __launch_bounds__(256) void k_select32(
    const float* __restrict__ Aq, const float* __restrict__ Bb,
    const float* __restrict__ content,
    const int* __restrict__ cand_v, const int* __restrict__ cand_c,
    float* __restrict__ out)
{
  __shared__ int    s_s[NCAND];
  __shared__ int    s_c[NCAND];
  __shared__ float  s_q[KDIM];
  __shared__ int    w_v[4], w_c[4], w_p[4];
  __shared__ int    sel_c[RSC];
  __shared__ double sel_v[RSC];
  __shared__ int    o_col[TOPK], o_ok[TOPK];

  const int tid = threadIdx.x;
  const int b   = blockIdx.x;
  const int wid = tid >> 6, lane = tid & 63;

  size_t cbase = (size_t)b * NCAND;
  for (int i = tid; i < NCAND; i += 256) { s_s[i] = cand_v[cbase + i]; s_c[i] = cand_c[cbase + i]; }
  for (int i = tid; i < KDIM; i += 256) s_q[i] = Aq[(size_t)b * KDIM + i];
  if (tid < TOPK) { o_ok[tid] = 0; o_col[tid] = 0; }
  __syncthreads();

  // 32 x argmax over int scores (tie -> lowest col); wave-shuffle + 4-wave merge
  for (int k = 0; k < RSC; ++k) {
    int best = INT_MIN, bc = 0x7FFFFFFF, bp = 0;
    for (int i = tid; i < NCAND; i += 256) {
      int v = s_s[i], cc = s_c[i];
      if (v > best || (v == best && cc < bc)) { best = v; bc = cc; bp = i; }
    }
    #pragma unroll
    for (int off = 32; off > 0; off >>= 1) {
      int v2 = __shfl_xor(best, off); int c2 = __shfl_xor(bc, off); int p2 = __shfl_xor(bp, off);
      if (v2 > best || (v2 == best && c2 < bc)) { best = v2; bc = c2; bp = p2; }
    }
    if (lane == 0) { w_v[wid] = best; w_c[wid] = bc; w_p[wid] = bp; }
    __syncthreads();
    if (tid == 0) {
      int bv = w_v[0], bcc = w_c[0], bpp = w_p[0];
      #pragma unroll
      for (int ww = 1; ww < 4; ++ww)
        if (w_v[ww] > bv || (w_v[ww] == bv && w_c[ww] < bcc)) { bv = w_v[ww]; bcc = w_c[ww]; bpp = w_p[ww]; }
      sel_c[k] = bcc; s_s[bpp] = INT_MIN;
    }
    __syncthreads();
  }

  // exact fp64 rescore: 4 waves x 8 candidates
  for (int q = 0; q < 8; ++q) {
    int i  = wid * 8 + q;
    int cc = sel_c[i];
    bool ok = (cc >= 0 && cc < CAP);
    double a = 0.0;
    if (ok) {
      const float* brow = &Bb[(size_t)cc * KDIM];
      #pragma unroll 4
      for (int j = 0; j < KDIM / 64; ++j) {
        int kk = j * 64 + lane;
        a += (double)s_q[kk] * (double)brow[kk];
      }
    }
    #pragma unroll
    for (int off = 32; off > 0; off >>= 1) a += __shfl_down(a, off);
    if (lane == 0) sel_v[i] = ok ? a : -INFINITY;
  }
  __syncthreads();

  // exact ranking of the 32 (score desc, col asc, pos asc), emit top-5
  if (tid < RSC) {
    double my = sel_v[tid]; int mc = sel_c[tid];
    int rank = 0;
    for (int j = 0; j < RSC; ++j) {
      double ov = sel_v[j]; int oc = sel_c[j];
      if (ov > my || (ov == my && (oc < mc || (oc == mc && j < tid)))) ++rank;
    }
    if (rank < TOPK) {
      double simv = my * (1.0 / 40.0);
      int pass = (my != -INFINITY) && (simv >= 0.3);
      out[(size_t)BQ * TOPK * CDIM + (size_t)b * TOPK + rank] = pass ? (float)simv : 0.0f;
      o_col[rank] = mc; o_ok[rank] = pass;
    }
  }
  __syncthreads();

  for (int idx = tid; idx < TOPK * CDIM; idx += 256) {
    int slot = idx / CDIM;
    int d    = idx - slot * CDIM;
    float v  = 0.f;
    if (o_ok[slot]) v = content[(size_t)o_col[slot] * CDIM + d];
    out[(size_t)b * TOPK * CDIM + idx] = v;
  }
}

// ---------------- fallback: round-2 proven fp32 path ----------------
__global__ __launch_bounds__(256) void k_gemm_cand(
    const float* __restrict__ Aq, const float* __restrict__ Bb,
    const int* __restrict__ valid,
    float* __restrict__ cand_s, int* __restrict__ cand_c)
{
  __shared__ __align__(16) unsigned char smem[128*SIMPAD*4];
  __shared__ int s_valid[128];
  unsigned short* lds_a = (unsigned short*)smem;
  unsigned short* lds_b = lds_a + 128*KPAD;
  float* sim = (float*)smem;

  const int tid = threadIdx.x;
  const int bid = blockIdx.x;
  const int rt = bid & 7;
  const int ct = bid >> 3;
  const int lane = tid & 63;
  const int wid  = tid >> 6;
  const int wr = wid >> 1;
  const int wc = wid & 1;
  const int lrow = lane & 15;
  const int lko  = (lane >> 4) * 8;

  const int arow0 = rt * 128;
  const int brow0 = ct * 128;

  if (tid < 128) {
    int col = brow0 + tid;
    s_valid[tid] = (col < CAP) ? valid[col] : 0;
  }

  f32x4 acc[4][4];
  const f32x4 zero4 = {0.f, 0.f, 0.f, 0.f};
  #pragma unroll
  for (int m = 0; m < 4; ++m)
    #pragma unroll
    for (int n = 0; n < 4; ++n) acc[m][n] = zero4;

  for (int k0 = 0; k0 < KDIM; k0 += 32) {
    #pragma unroll
    for (int it = 0; it < 4; ++it) {
      int idx = it * 256 + tid;
      int row = idx >> 3;
      int kq  = (idx & 7) * 4;
      float4 av = *reinterpret_cast<const float4*>(&Aq[(size_t)(arow0 + row) * KDIM + k0 + kq]);
      ushort4 pa = make_ushort4(f2bf(av.x), f2bf(av.y), f2bf(av.z), f2bf(av.w));
      *reinterpret_cast<ushort4*>(&lds_a[row * KPAD + kq]) = pa;
      int br = brow0 + row;
      float4 bv = make_float4(0.f, 0.f, 0.f, 0.f);
      if (br < CAP) bv = *reinterpret_cast<const float4*>(&Bb[(size_t)br * KDIM + k0 + kq]);
      ushort4 pb = make_ushort4(f2bf(bv.x), f2bf(bv.y), f2bf(bv.z), f2bf(bv.w));
      *reinterpret_cast<ushort4*>(&lds_b[row * KPAD + kq]) = pb;
    }
    __syncthreads();

    bf16x8 af2[4], bf2[4];
    #pragma unroll
    for (int m = 0; m < 4; ++m)
      af2[m] = *reinterpret_cast<const bf16x8*>(&lds_a[(wr*64 + m*16 + lrow) * KPAD + lko]);
    #pragma unroll
    for (int n = 0; n < 4; ++n)
      bf2[n] = *reinterpret_cast<const bf16x8*>(&lds_b[(wc*64 + n*16 + lrow) * KPAD + lko]);

    #pragma unroll
    for (int m = 0; m < 4; ++m)
      #pragma unroll
      for (int n = 0; n < 4; ++n)
        acc[m][n] = __builtin_amdgcn_mfma_f32_16x16x32_bf16(af2[m], bf2[n], acc[m][n], 0, 0, 0);
    __syncthreads();
  }

  #pragma unroll
  for (int m = 0; m < 4; ++m) {
    #pragma unroll
    for (int n = 0; n < 4; ++n) {
      int col  = wc*64 + n*16 + (lane & 15);
      int rowb = wr*64 + m*16 + (lane >> 4) * 4;
      #pragma unroll
      for (int r = 0; r < 4; ++r)
        sim[(rowb + r) * SIMPAD + col] = acc[m][n][r];
    }
  }
  __syncthreads();

  if (tid < 128) {
    float s[TOPK]; int c[TOPK];
    #pragma unroll
    for (int i = 0; i < TOPK; ++i) { s[i] = -INFINITY; c[i] = 0x7FFFFFFF; }
    for (int j = 0; j < 128; ++j) {
      int col = brow0 + j;
      if (col >= CAP) break;
      if (!s_valid[j]) continue;
      float v = sim[tid * SIMPAD + j];
      if (v > s[TOPK-1]) {
        int p = TOPK - 1;
        while (p > 0 && v > s[p-1]) { s[p] = s[p-1]; c[p] = c[p-1]; --p; }
        s[p] = v; c[p] = col;
      }
    }
    size_t base = ((size_t)(arow0 + tid) * NT + ct) * TOPK;
    #pragma unroll
    for (int i = 0; i < TOPK; ++i) { cand_s[base + i] = s[i]; cand_c[base + i] = c[i]; }
  }
}

__global__ __launch_bounds__(256) void k_select(
    const float* __restrict__ Aq, const float* __restrict__ Bb,
    const float* __restrict__ content,
    const float* __restrict__ cand_s, const int* __restrict__ cand_c,
    float* __restrict__ out)
{
  __shared__ float  s_s[NCAND];
  __shared__ int    s_c[NCAND];
  __shared__ float  s_q[KDIM];
  __shared__ float  r_s[256];
  __shared__ int    r_c[256];
  __shared__ int    r_p[256];
  __shared__ int    sel_c[32];
  __shared__ double sel_v[32];
  __shared__ int    o_col[TOPK];
  __shared__ int    o_ok[TOPK];

  const int tid = threadIdx.x;
  const int b   = blockIdx.x;

  size_t cbase = (size_t)b * NCAND;
  for (int i = tid; i < NCAND; i += 256) { s_s[i] = cand_s[cbase + i]; s_c[i] = cand_c[cbase + i]; }
  for (int i = tid; i < KDIM; i += 256) s_q[i] = Aq[(size_t)b * KDIM + i];
  if (tid < TOPK) { o_ok[tid] = 0; o_col[tid] = 0; }
  __syncthreads();

  for (int k = 0; k < 32; ++k) {
    float best = -INFINITY; int bc = 0x7FFFFFFF; int bp = 0;
    for (int i = tid; i < NCAND; i += 256) {
      float v = s_s[i]; int cc = s_c[i];
      if (v > best || (v == best && cc < bc)) { best = v; bc = cc; bp = i; }
    }
    r_s[tid] = best; r_c[tid] = bc; r_p[tid] = bp;
    __syncthreads();
    for (int off = 128; off > 0; off >>= 1) {
      if (tid < off) {
        float v = r_s[tid + off]; int cc = r_c[tid + off];
        if (v > r_s[tid] || (v == r_s[tid] && cc < r_c[tid])) {
          r_s[tid] = v; r_c[tid] = cc; r_p[tid] = r_p[tid + off];
        }
      }
      __syncthreads();
    }
    if (tid == 0) { sel_c[k] = r_c[0]; s_s[r_p[0]] = -INFINITY; }
    __syncthreads();
  }

  const int wid = tid >> 6, lane = tid & 63;
  for (int q = 0; q < 8; ++q) {
    int i  = wid * 8 + q;
    int cc = sel_c[i];
    bool ok = (cc >= 0 && cc < CAP);
    double a = 0.0;
    if (ok) {
      const float* brow = &Bb[(size_t)cc * KDIM];
      #pragma unroll 4
      for (int j = 0; j < KDIM / 64; ++j) {
        int kk = j * 64 + lane;
        a += (double)s_q[kk] * (double)brow[kk];
      }
    }
    #pragma unroll
    for (int off = 32; off > 0; off >>= 1) a += __shfl_down(a, off);
    if (lane == 0) sel_v[i] = ok ? a : -INFINITY;
  }
  __syncthreads();

  if (tid < 32) {
    double my = sel_v[tid]; int mc = sel_c[tid];
    int rank = 0;
    for (int j = 0; j < 32; ++j) {
      double ov = sel_v[j]; int oc = sel_c[j];
      if (ov > my || (ov == my && (oc < mc || (oc == mc && j < tid)))) ++rank;
    }
    if (rank < TOPK) {
      double simv = my * (1.0 / 40.0);
      int pass = (my != -INFINITY) && (simv >= 0.3);
      out[(size_t)BQ * TOPK * CDIM + (size_t)b * TOPK + rank] = pass ? (float)simv : 0.0f;
      o_col[rank] = mc; o_ok[rank] = pass;
    }
  }
  __syncthreads();

  for (int idx = tid; idx < TOPK * CDIM; idx += 256) {
    int slot = idx / CDIM;
    int d    = idx - slot * CDIM;
    float v  = 0.f;
    if (o_ok[slot]) v = content[(size_t)o_col[slot] * CDIM + d];
    out[(size_t)b * TOPK * CDIM + idx] = v;
  }
}

extern "C" void kernel_launch(void* const* d_in, const int* in_sizes, int n_in,
                              void* d_out, int out_size, void* d_ws, size_t ws_size,
                              hipStream_t stream) {
  const float* q        = (const float*)d_in[0];
  const float* bank     = (const float*)d_in[1];
  const float* content  = (const float*)d_in[2];
  const int*   valid    = (const int*)d_in[3];
  float* out = (float*)d_out;

  if (ws_size >= WSI_NEED) {
    unsigned char* Bt = (unsigned char*)d_ws + WSI_B;
    unsigned char* At = (unsigned char*)d_ws + WSI_A;
    int* cand_v = (int*)((char*)d_ws + WSI_CV);
    int* cand_c = (int*)((char*)d_ws + WSI_CC);

    k_cvt_i8<<<dim3(4096), dim3(256), 0, stream>>>(bank, Bt, NT * 16384, CAP);
    k_cvt_i8<<<dim3(512),  dim3(256), 0, stream>>>(q,    At, MT * 16384, BQ);
    k_gemm_i8<<<dim3(98 * 64), dim3(256), 0, stream>>>(At, Bt, valid, cand_v, cand_c);
    k_select32<<<dim3(BQ), dim3(256), 0, stream>>>(q, bank, content, cand_v, cand_c, out);
  } else {
    float* cand_s = (float*)d_ws;
    int*   cand_c = (int*)((char*)d_ws + (size_t)BQ * NCAND * 4);
    k_gemm_cand<<<dim3(MT * NT), dim3(256), 0, stream>>>(q, bank, valid, cand_s, cand_c);
    k_select<<<dim3(BQ), dim3(256), 0, stream>>>(q, bank, content, cand_s, cand_c, out);
  }
}

// Round 6
// 701.732 us; speedup vs baseline: 4.2417x; 1.4341x over previous
//
#include <hip/hip_runtime.h>
#include <hip/hip_bf16.h>
#include <math.h>
#include <limits.h>

#define BQ   1024
#define CAP  100000
#define KDIM 2048
#define CDIM 384
#define TOPK 5
#define MT   8
#define NT   782            // ceil(100000/128)
#define NCAND (NT*TOPK)     // 3910
#define NKT  32             // K-tiles of 64 i8
#define RSC  16             // rescore set size
// fallback (round-2 proven) params
#define KPAD 56
#define SIMPAD 129

// i8 path ws layout (bytes)
#define WSI_B    0UL            // 782 tiles * 262144 = 205,000,704
#define WSI_A    205000704UL    // 8 tiles * 262144   = 2,097,152
#define WSI_CV   207097856UL    // 1024*3910*4
#define WSI_CC   223113216UL    // 1024*3910*4
#define WSI_NEED 239128576UL

typedef int    int4v  __attribute__((ext_vector_type(4)));
typedef float  f32x4  __attribute__((ext_vector_type(4)));
typedef __bf16 bf16x8 __attribute__((ext_vector_type(8)));

__device__ __forceinline__ unsigned short f2bf(float f) {
  unsigned int u = __float_as_uint(f);
  u += 0x7FFF + ((u >> 16) & 1);
  return (unsigned short)(u >> 16);
}

// ---------------- K0: fp32 -> i8 (x127) into tiled+chunk-XOR'd layout ----------------
// Per 128-row tile (262144 B): [kt 0..31][row 0..127][stored-chunk 0..3][16 B].
// stored chunk sc holds logical chunk lc = sc ^ ((row>>1)&3)  (XOR involution).
__global__ __launch_bounds__(256) void k_cvt_i8(const float* __restrict__ src,
                                                unsigned char* __restrict__ dst,
                                                int nchunks, int nrows) {
  int stride = gridDim.x * 256;
  for (int g = blockIdx.x * 256 + threadIdx.x; g < nchunks; g += stride) {
    int tile = g >> 14;          // 16384 16B-chunks per tile
    int rem  = g & 16383;
    int kt   = rem >> 9;         // 512 chunks per K-tile (128 rows x 4)
    int loc  = rem & 511;
    int row  = loc >> 2;
    int sc   = loc & 3;
    int lc   = sc ^ ((row >> 1) & 3);
    int srcRow = tile * 128 + row;
    unsigned int w0 = 0, w1 = 0, w2 = 0, w3 = 0;
    if (srcRow < nrows) {
      const float* sp = src + (size_t)srcRow * KDIM + kt * 64 + lc * 16;
      float4 a = *reinterpret_cast<const float4*>(sp);
      float4 b = *reinterpret_cast<const float4*>(sp + 4);
      float4 c = *reinterpret_cast<const float4*>(sp + 8);
      float4 d = *reinterpret_cast<const float4*>(sp + 12);
      #define Q8(x) ((unsigned int)(int)((x) * 127.f + 0.5f))
      w0 = Q8(a.x) | (Q8(a.y) << 8) | (Q8(a.z) << 16) | (Q8(a.w) << 24);
      w1 = Q8(b.x) | (Q8(b.y) << 8) | (Q8(b.z) << 16) | (Q8(b.w) << 24);
      w2 = Q8(c.x) | (Q8(c.y) << 8) | (Q8(c.z) << 16) | (Q8(c.w) << 24);
      w3 = Q8(d.x) | (Q8(d.y) << 8) | (Q8(d.z) << 16) | (Q8(d.w) << 24);
      #undef Q8
    }
    *reinterpret_cast<uint4*>(dst + (size_t)g * 16) = make_uint4(w0, w1, w2, w3);
  }
}

// ---------------- K1: i8 MFMA GEMM, 2-phase double-buffered (T3 minimum recipe) ----------
__global__ __launch_bounds__(256) void k_gemm_i8(
    const unsigned char* __restrict__ At, const unsigned char* __restrict__ Bt,
    const int* __restrict__ valid,
    int* __restrict__ cand_v, int* __restrict__ cand_c)
{
  // dbuf: buf c at c*16384 {A 8KB | B 8KB}; epilogue sim [128][33] i32 aliases smem
  __shared__ __align__(16) unsigned char smem[32768];
  __shared__ int s_valid[128];
  int* sim = (int*)smem;

  const int bid = blockIdx.x;
  const int g = bid >> 6, sub = bid & 63;
  const int rt = sub >> 3;
  const int ct = g * 8 + (sub & 7);     // bid%8 == ct%8 -> B-tile sharers on one XCD
  if (ct >= NT) return;

  const int tid = threadIdx.x;
  const int lane = tid & 63;
  const int w    = tid >> 6;
  const int wr = w >> 1, wc = w & 1;
  const int lrow = lane & 15;
  // stored-chunk byte offset for this lane's K-chunk (XOR involution, lane-only)
  const int swc = (((lane >> 4) ^ ((lrow >> 1) & 3)) << 4);

  const int arow0 = rt * 128, brow0 = ct * 128;
  if (tid < 128) s_valid[tid] = (brow0 + tid < CAP) ? valid[brow0 + tid] : 0;

  int4v acc[4][4];
  const int4v z4 = {0, 0, 0, 0};
  #pragma unroll
  for (int m = 0; m < 4; ++m)
    #pragma unroll
    for (int n = 0; n < 4; ++n) acc[m][n] = z4;

  const unsigned char* gAt = At + (size_t)rt * 262144;
  const unsigned char* gBt = Bt + (size_t)ct * 262144;

  // stage K-tile kt into buffer b (wave-uniform LDS base; lane lands at +lane*16)
  auto STG = [&](int b, int kt) {
    #pragma unroll
    for (int j = 0; j < 2; ++j) {
      const unsigned char* sA = gAt + kt * 8192 + j * 4096 + tid * 16;
      unsigned char* dA = smem + b * 16384 + j * 4096 + w * 1024;
      __builtin_amdgcn_global_load_lds(
          (const __attribute__((address_space(1))) unsigned int*)sA,
          (__attribute__((address_space(3))) unsigned int*)dA, 16, 0, 0);
      const unsigned char* sB = gBt + kt * 8192 + j * 4096 + tid * 16;
      unsigned char* dB = smem + b * 16384 + 8192 + j * 4096 + w * 1024;
      __builtin_amdgcn_global_load_lds(
          (const __attribute__((address_space(1))) unsigned int*)sB,
          (__attribute__((address_space(3))) unsigned int*)dB, 16, 0, 0);
    }
  };

  STG(0, 0);
  __syncthreads();   // vmcnt(0): tile 0 resident

  for (int kt = 0; kt < NKT; ++kt) {
    const int cur = kt & 1;
    // issue next-tile staging FIRST -> HBM latency hides under ds_read + MFMA
    if (kt + 1 < NKT) STG(cur ^ 1, kt + 1);

    const unsigned char* la = smem + cur * 16384;
    const unsigned char* lb = la + 8192;
    int4v af[4], bfr[4];
    #pragma unroll
    for (int m = 0; m < 4; ++m)
      af[m] = *reinterpret_cast<const int4v*>(la + (wr*64 + m*16 + lrow) * 64 + swc);
    #pragma unroll
    for (int n = 0; n < 4; ++n)
      bfr[n] = *reinterpret_cast<const int4v*>(lb + (wc*64 + n*16 + lrow) * 64 + swc);

    #pragma unroll
    for (int m = 0; m < 4; ++m)
      #pragma unroll
      for (int n = 0; n < 4; ++n)
        acc[m][n] = __builtin_amdgcn_mfma_i32_16x16x64_i8(af[m], bfr[n], acc[m][n], 0, 0, 0);

    __syncthreads();   // single drain per iter: next tile resident, frag reads done
  }

  // epilogue: 4 chunks of 32 cols via [128][33] i32 slab; running top-5 in regs
  int ts[TOPK]; int tc[TOPK];
  #pragma unroll
  for (int i = 0; i < TOPK; ++i) { ts[i] = INT_MIN; tc[i] = 0x7FFFFFFF; }

  for (int c = 0; c < 4; ++c) {
    __syncthreads();
    if (wc == (c >> 1)) {
      #pragma unroll
      for (int m = 0; m < 4; ++m) {
        #pragma unroll
        for (int nn = 0; nn < 2; ++nn) {
          int n = (c & 1) * 2 + nn;
          int rowb = wr*64 + m*16 + (lane >> 4) * 4;
          int lcol = nn*16 + lrow;
          #pragma unroll
          for (int r = 0; r < 4; ++r)
            sim[(rowb + r) * 33 + lcol] = acc[m][n][r];
        }
      }
    }
    __syncthreads();
    if (tid < 128) {
      #pragma unroll 4
      for (int j = 0; j < 32; ++j) {
        int jj = c * 32 + j;
        int v = sim[tid * 33 + j];
        if (s_valid[jj] && v > ts[TOPK-1]) {
          int col = brow0 + jj;
          int p = TOPK - 1;
          while (p > 0 && v > ts[p-1]) { ts[p] = ts[p-1]; tc[p] = tc[p-1]; --p; }
          ts[p] = v; tc[p] = col;
        }
      }
    }
  }

  if (tid < 128) {
    size_t base = ((size_t)(arow0 + tid) * NT + ct) * TOPK;
    #pragma unroll
    for (int i = 0; i < TOPK; ++i) { cand_v[base + i] = ts[i]; cand_c[base + i] = tc[i]; }
  }
}

// ---------------- K2: merge int candidates -> top-16 -> exact fp64 rescore -> output --------
__global__ __launch_bounds__(256) void k_select16(
    const float* __restrict__ Aq, const float* __restrict__ Bb,
    const float* __restrict__ content,
    const int* __restrict__ cand_v, const int* __restrict__ cand_c,
    float* __restrict__ out)
{
  __shared__ int    s_s[NCAND];
  __shared__ int    s_c[NCAND];
  __shared__ float  s_q[KDIM];
  __shared__ int    w_v[4], w_c[4], w_p[4];
  __shared__ int    sel_c[RSC];
  __shared__ double sel_v[RSC];
  __shared__ int    o_col[TOPK], o_ok[TOPK];

  const int tid = threadIdx.x;
  const int b   = blockIdx.x;
  const int wid = tid >> 6, lane = tid & 63;

  size_t cbase = (size_t)b * NCAND;
  for (int i = tid; i < NCAND; i += 256) { s_s[i] = cand_v[cbase + i]; s_c[i] = cand_c[cbase + i]; }
  for (int i = tid; i < KDIM; i += 256) s_q[i] = Aq[(size_t)b * KDIM + i];
  if (tid < TOPK) { o_ok[tid] = 0; o_col[tid] = 0; }
  __syncthreads();

  // 16 x argmax over int scores (tie -> lowest col); wave-shuffle + 4-wave merge
  for (int k = 0; k < RSC; ++k) {
    int best = INT_MIN, bc = 0x7FFFFFFF, bp = 0;
    for (int i = tid; i < NCAND; i += 256) {
      int v = s_s[i], cc = s_c[i];
      if (v > best || (v == best && cc < bc)) { best = v; bc = cc; bp = i; }
    }
    #pragma unroll
    for (int off = 32; off > 0; off >>= 1) {
      int v2 = __shfl_xor(best, off); int c2 = __shfl_xor(bc, off); int p2 = __shfl_xor(bp, off);
      if (v2 > best || (v2 == best && c2 < bc)) { best = v2; bc = c2; bp = p2; }
    }
    if (lane == 0) { w_v[wid] = best; w_c[wid] = bc; w_p[wid] = bp; }
    __syncthreads();
    if (tid == 0) {
      int bv = w_v[0], bcc = w_c[0], bpp = w_p[0];
      #pragma unroll
      for (int ww = 1; ww < 4; ++ww)
        if (w_v[ww] > bv || (w_v[ww] == bv && w_c[ww] < bcc)) { bv = w_v[ww]; bcc = w_c[ww]; bpp = w_p[ww]; }
      sel_c[k] = bcc; s_s[bpp] = INT_MIN;
    }
    __syncthreads();
  }

  // exact fp64 rescore: 4 waves x 4 candidates
  for (int q = 0; q < 4; ++q) {
    int i  = wid * 4 + q;
    int cc = sel_c[i];
    bool ok = (cc >= 0 && cc < CAP);
    double a = 0.0;
    if (ok) {
      const float* brow = &Bb[(size_t)cc * KDIM];
      #pragma unroll 4
      for (int j = 0; j < KDIM / 64; ++j) {
        int kk = j * 64 + lane;
        a += (double)s_q[kk] * (double)brow[kk];
      }
    }
    #pragma unroll
    for (int off = 32; off > 0; off >>= 1) a += __shfl_down(a, off);
    if (lane == 0) sel_v[i] = ok ? a : -INFINITY;
  }
  __syncthreads();

  // exact ranking of the 16 (score desc, col asc, pos asc), emit top-5
  if (tid < RSC) {
    double my = sel_v[tid]; int mc = sel_c[tid];
    int rank = 0;
    for (int j = 0; j < RSC; ++j) {
      double ov = sel_v[j]; int oc = sel_c[j];
      if (ov > my || (ov == my && (oc < mc || (oc == mc && j < tid)))) ++rank;
    }
    if (rank < TOPK) {
      double simv = my * (1.0 / 40.0);
      int pass = (my != -INFINITY) && (simv >= 0.3);
      out[(size_t)BQ * TOPK * CDIM + (size_t)b * TOPK + rank] = pass ? (float)simv : 0.0f;
      o_col[rank] = mc; o_ok[rank] = pass;
    }
  }
  __syncthreads();

  for (int idx = tid; idx < TOPK * CDIM; idx += 256) {
    int slot = idx / CDIM;
    int d    = idx - slot * CDIM;
    float v  = 0.f;
    if (o_ok[slot]) v = content[(size_t)o_col[slot] * CDIM + d];
    out[(size_t)b * TOPK * CDIM + idx] = v;
  }
}

// ---------------- fallback: round-2 proven fp32 path ----------------
__global__ __launch_bounds__(256) void k_gemm_cand(
    const float* __restrict__ Aq, const float* __restrict__ Bb,
    const int* __restrict__ valid,
    float* __restrict__ cand_s, int* __restrict__ cand_c)
{
  __shared__ __align__(16) unsigned char smem[128*SIMPAD*4];
  __shared__ int s_valid[128];
  unsigned short* lds_a = (unsigned short*)smem;
  unsigned short* lds_b = lds_a + 128*KPAD;
  float* sim = (float*)smem;

  const int tid = threadIdx.x;
  const int bid = blockIdx.x;
  const int rt = bid & 7;
  const int ct = bid >> 3;
  const int lane = tid & 63;
  const int wid  = tid >> 6;
  const int wr = wid >> 1;
  const int wc = wid & 1;
  const int lrow = lane & 15;
  const int lko  = (lane >> 4) * 8;

  const int arow0 = rt * 128;
  const int brow0 = ct * 128;

  if (tid < 128) {
    int col = brow0 + tid;
    s_valid[tid] = (col < CAP) ? valid[col] : 0;
  }

  f32x4 acc[4][4];
  const f32x4 zero4 = {0.f, 0.f, 0.f, 0.f};
  #pragma unroll
  for (int m = 0; m < 4; ++m)
    #pragma unroll
    for (int n = 0; n < 4; ++n) acc[m][n] = zero4;

  for (int k0 = 0; k0 < KDIM; k0 += 32) {
    #pragma unroll
    for (int it = 0; it < 4; ++it) {
      int idx = it * 256 + tid;
      int row = idx >> 3;
      int kq  = (idx & 7) * 4;
      float4 av = *reinterpret_cast<const float4*>(&Aq[(size_t)(arow0 + row) * KDIM + k0 + kq]);
      ushort4 pa = make_ushort4(f2bf(av.x), f2bf(av.y), f2bf(av.z), f2bf(av.w));
      *reinterpret_cast<ushort4*>(&lds_a[row * KPAD + kq]) = pa;
      int br = brow0 + row;
      float4 bv = make_float4(0.f, 0.f, 0.f, 0.f);
      if (br < CAP) bv = *reinterpret_cast<const float4*>(&Bb[(size_t)br * KDIM + k0 + kq]);
      ushort4 pb = make_ushort4(f2bf(bv.x), f2bf(bv.y), f2bf(bv.z), f2bf(bv.w));
      *reinterpret_cast<ushort4*>(&lds_b[row * KPAD + kq]) = pb;
    }
    __syncthreads();

    bf16x8 af2[4], bf2[4];
    #pragma unroll
    for (int m = 0; m < 4; ++m)
      af2[m] = *reinterpret_cast<const bf16x8*>(&lds_a[(wr*64 + m*16 + lrow) * KPAD + lko]);
    #pragma unroll
    for (int n = 0; n < 4; ++n)
      bf2[n] = *reinterpret_cast<const bf16x8*>(&lds_b[(wc*64 + n*16 + lrow) * KPAD + lko]);

    #pragma unroll
    for (int m = 0; m < 4; ++m)
      #pragma unroll
      for (int n = 0; n < 4; ++n)
        acc[m][n] = __builtin_amdgcn_mfma_f32_16x16x32_bf16(af2[m], bf2[n], acc[m][n], 0, 0, 0);
    __syncthreads();
  }

  #pragma unroll
  for (int m = 0; m < 4; ++m) {
    #pragma unroll
    for (int n = 0; n < 4; ++n) {
      int col  = wc*64 + n*16 + (lane & 15);
      int rowb = wr*64 + m*16 + (lane >> 4) * 4;
      #pragma unroll
      for (int r = 0; r < 4; ++r)
        sim[(rowb + r) * SIMPAD + col] = acc[m][n][r];
    }
  }
  __syncthreads();

  if (tid < 128) {
    float s[TOPK]; int c[TOPK];
    #pragma unroll
    for (int i = 0; i < TOPK; ++i) { s[i] = -INFINITY; c[i] = 0x7FFFFFFF; }
    for (int j = 0; j < 128; ++j) {
      int col = brow0 + j;
      if (col >= CAP) break;
      if (!s_valid[j]) continue;
      float v = sim[tid * SIMPAD + j];
      if (v > s[TOPK-1]) {
        int p = TOPK - 1;
        while (p > 0 && v > s[p-1]) { s[p] = s[p-1]; c[p] = c[p-1]; --p; }
        s[p] = v; c[p] = col;
      }
    }
    size_t base = ((size_t)(arow0 + tid) * NT + ct) * TOPK;
    #pragma unroll
    for (int i = 0; i < TOPK; ++i) { cand_s[base + i] = s[i]; cand_c[base + i] = c[i]; }
  }
}

__global__ __launch_bounds__(256) void k_select(
    const float* __restrict__ Aq, const float* __restrict__ Bb,
    const float* __restrict__ content,
    const float* __restrict__ cand_s, const int* __restrict__ cand_c,
    float* __restrict__ out)
{
  __shared__ float  s_s[NCAND];
  __shared__ int    s_c[NCAND];
  __shared__ float  s_q[KDIM];
  __shared__ float  r_s[256];
  __shared__ int    r_c[256];
  __shared__ int    r_p[256];
  __shared__ int    sel_c[32];
  __shared__ double sel_v[32];
  __shared__ int    o_col[TOPK];
  __shared__ int    o_ok[TOPK];

  const int tid = threadIdx.x;
  const int b   = blockIdx.x;

  size_t cbase = (size_t)b * NCAND;
  for (int i = tid; i < NCAND; i += 256) { s_s[i] = cand_s[cbase + i]; s_c[i] = cand_c[cbase + i]; }
  for (int i = tid; i < KDIM; i += 256) s_q[i] = Aq[(size_t)b * KDIM + i];
  if (tid < TOPK) { o_ok[tid] = 0; o_col[tid] = 0; }
  __syncthreads();

  for (int k = 0; k < 32; ++k) {
    float best = -INFINITY; int bc = 0x7FFFFFFF; int bp = 0;
    for (int i = tid; i < NCAND; i += 256) {
      float v = s_s[i]; int cc = s_c[i];
      if (v > best || (v == best && cc < bc)) { best = v; bc = cc; bp = i; }
    }
    r_s[tid] = best; r_c[tid] = bc; r_p[tid] = bp;
    __syncthreads();
    for (int off = 128; off > 0; off >>= 1) {
      if (tid < off) {
        float v = r_s[tid + off]; int cc = r_c[tid + off];
        if (v > r_s[tid] || (v == r_s[tid] && cc < r_c[tid])) {
          r_s[tid] = v; r_c[tid] = cc; r_p[tid] = r_p[tid + off];
        }
      }
      __syncthreads();
    }
    if (tid == 0) { sel_c[k] = r_c[0]; s_s[r_p[0]] = -INFINITY; }
    __syncthreads();
  }

  const int wid = tid >> 6, lane = tid & 63;
  for (int q = 0; q < 8; ++q) {
    int i  = wid * 8 + q;
    int cc = sel_c[i];
    bool ok = (cc >= 0 && cc < CAP);
    double a = 0.0;
    if (ok) {
      const float* brow = &Bb[(size_t)cc * KDIM];
      #pragma unroll 4
      for (int j = 0; j < KDIM / 64; ++j) {
        int kk = j * 64 + lane;
        a += (double)s_q[kk] * (double)brow[kk];
      }
    }
    #pragma unroll
    for (int off = 32; off > 0; off >>= 1) a += __shfl_down(a, off);
    if (lane == 0) sel_v[i] = ok ? a : -INFINITY;
  }
  __syncthreads();

  if (tid < 32) {
    double my = sel_v[tid]; int mc = sel_c[tid];
    int rank = 0;
    for (int j = 0; j < 32; ++j) {
      double ov = sel_v[j]; int oc = sel_c[j];
      if (ov > my || (ov == my && (oc < mc || (oc == mc && j < tid)))) ++rank;
    }
    if (rank < TOPK) {
      double simv = my * (1.0 / 40.0);
      int pass = (my != -INFINITY) && (simv >= 0.3);
      out[(size_t)BQ * TOPK * CDIM + (size_t)b * TOPK + rank] = pass ? (float)simv : 0.0f;
      o_col[rank] = mc; o_ok[rank] = pass;
    }
  }
  __syncthreads();

  for (int idx = tid; idx < TOPK * CDIM; idx += 256) {
    int slot = idx / CDIM;
    int d    = idx - slot * CDIM;
    float v  = 0.f;
    if (o_ok[slot]) v = content[(size_t)o_col[slot] * CDIM + d];
    out[(size_t)b * TOPK * CDIM + idx] = v;
  }
}

extern "C" void kernel_launch(void* const* d_in, const int* in_sizes, int n_in,
                              void* d_out, int out_size, void* d_ws, size_t ws_size,
                              hipStream_t stream) {
  const float* q        = (const float*)d_in[0];
  const float* bank     = (const float*)d_in[1];
  const float* content  = (const float*)d_in[2];
  const int*   valid    = (const int*)d_in[3];
  float* out = (float*)d_out;

  if (ws_size >= WSI_NEED) {
    unsigned char* Bt = (unsigned char*)d_ws + WSI_B;
    unsigned char* At = (unsigned char*)d_ws + WSI_A;
    int* cand_v = (int*)((char*)d_ws + WSI_CV);
    int* cand_c = (int*)((char*)d_ws + WSI_CC);

    k_cvt_i8<<<dim3(4096), dim3(256), 0, stream>>>(bank, Bt, NT * 16384, CAP);
    k_cvt_i8<<<dim3(512),  dim3(256), 0, stream>>>(q,    At, MT * 16384, BQ);
    k_gemm_i8<<<dim3(98 * 64), dim3(256), 0, stream>>>(At, Bt, valid, cand_v, cand_c);
    k_select16<<<dim3(BQ), dim3(256), 0, stream>>>(q, bank, content, cand_v, cand_c, out);
  } else {
    float* cand_s = (float*)d_ws;
    int*   cand_c = (int*)((char*)d_ws + (size_t)BQ * NCAND * 4);
    k_gemm_cand<<<dim3(MT * NT), dim3(256), 0, stream>>>(q, bank, valid, cand_s, cand_c);
    k_select<<<dim3(BQ), dim3(256), 0, stream>>>(q, bank, content, cand_s, cand_c, out);
  }
}